// Round 4
// baseline (1702.899 us; speedup 1.0000x reference)
//
#include <hip/hip_runtime.h>
#include <hip/hip_bf16.h>
#include <math.h>
#include <stdint.h>

// ---- problem constants ----
#define SEQ   4096
#define DIMM  2048
#define NH    32
#define NKV   8
#define HD    64
#define NSP   1100   // 300 vertical + 800 slash (duplicates kept)
#define NSPP  1152   // padded to multiple of 64

typedef __bf16 bf16x8 __attribute__((ext_vector_type(8)));
typedef float  f32x4  __attribute__((ext_vector_type(4)));

// Split a run of 8 f32 into hi/lo bf16 fragments (hi+lo ~ f32 fidelity).
__device__ inline void split8(const float* __restrict__ p, bf16x8& h, bf16x8& l) {
#pragma unroll
    for (int i = 0; i < 8; ++i) {
        float v = p[i];
        __bf16 hv = (__bf16)v;
        h[i] = hv;
        l[i] = (__bf16)(v - (float)hv);
    }
}
// Load 4 consecutive elements as f32 from f32-or-bf16 memory.
__device__ inline f32x4 load4(const void* __restrict__ p, size_t idx, bool f) {
    if (f) return *(const f32x4*)((const float*)p + idx);
    const __bf16* b = (const __bf16*)p + idx;
    f32x4 v;
    v[0] = (float)b[0]; v[1] = (float)b[1]; v[2] = (float)b[2]; v[3] = (float)b[3];
    return v;
}

// =====================================================================
// Input-dtype detection: flag=1 -> f32 inputs/outputs, flag=0 -> bf16.
// f32 memory read as bf16 gives garbage exponents with certainty.
// =====================================================================
__global__ __launch_bounds__(256) void detect_k(const void* __restrict__ x,
                                                int* __restrict__ flag) {
    const __bf16* p = (const __bf16*)x;
    int tid = threadIdx.x;
    bool bad = false;
    for (int i = 0; i < 16; ++i) {
        float v = fabsf((float)p[tid * 16 + i]);
        if (!(v <= 1e10f)) bad = true;    // catches huge AND NaN
    }
    unsigned long long m = __ballot(bad);
    __shared__ unsigned long long w[4];
    if ((tid & 63) == 0) w[tid >> 6] = m;
    __syncthreads();
    if (tid == 0) flag[0] = ((w[0] | w[1] | w[2] | w[3]) != 0ULL) ? 1 : 0;
}

// =====================================================================
// Convert x to bf16, 8 elements/thread.
// =====================================================================
__global__ __launch_bounds__(256) void convert_x_k(const void* __restrict__ x,
                                                   __bf16* __restrict__ xb,
                                                   const int* __restrict__ flag) {
    int i0 = (blockIdx.x * 256 + threadIdx.x) * 8;
    if (*flag) {
        const float* xf = (const float*)x;
        bf16x8 o;
        for (int i = 0; i < 8; ++i) o[i] = (__bf16)xf[i0 + i];
        *(bf16x8*)(xb + i0) = o;
    } else {
        *(bf16x8*)(xb + i0) = *(const bf16x8*)((const __bf16*)x + i0);
    }
}

// =====================================================================
// Tile transpose + convert: out[c][r] = (bf16)in[r][c]
// =====================================================================
__global__ __launch_bounds__(256) void transpose_cvt_k(const void* __restrict__ in,
                                                       __bf16* __restrict__ out, int R, int C,
                                                       const int* __restrict__ flag) {
    __shared__ __bf16 tile[32][33];
    bool f = (*flag != 0);
    int cb = blockIdx.x * 32, rb = blockIdx.y * 32;
    int tx = threadIdx.x & 31, ty = threadIdx.x >> 5;   // 32 x 8
    for (int i = 0; i < 32; i += 8) {
        size_t idx = (size_t)(rb + ty + i) * C + cb + tx;
        float v = f ? ((const float*)in)[idx] : (float)((const __bf16*)in)[idx];
        tile[ty + i][tx] = (__bf16)v;
    }
    __syncthreads();
    for (int i = 0; i < 32; i += 8)
        out[(size_t)(cb + ty + i) * R + rb + tx] = tile[tx][ty + i];
}

// =====================================================================
// bf16 NT GEMM: C[M][N] = A[M][K] @ Bt[N][K]^T, f32 acc.
// Value path (Q, V, output projection).
// =====================================================================
__global__ __launch_bounds__(256) void gemm_nt_k(const __bf16* __restrict__ A,
                                                 const __bf16* __restrict__ Bt,
                                                 void* __restrict__ C, int M, int N, int K,
                                                 int f32out, const int* __restrict__ flag) {
    int bm = blockIdx.x, bn = blockIdx.y;
    __shared__ __bf16 As[128][72];
    __shared__ __bf16 Bs[128][72];
    int tid = threadIdx.x, wave = tid >> 6, lane = tid & 63;
    int quad = lane >> 4, l16 = lane & 15;
    int wm = (wave >> 1) * 64, wn = (wave & 1) * 64;
    const f32x4 z4 = {0.f, 0.f, 0.f, 0.f};
    f32x4 acc[4][4];
    for (int a = 0; a < 4; ++a) for (int b = 0; b < 4; ++b) acc[a][b] = z4;
    int srow = tid >> 1, sk0 = (tid & 1) * 32;
    const __bf16* Ap = A  + (size_t)(bm * 128 + srow) * K + sk0;
    const __bf16* Bp = Bt + (size_t)(bn * 128 + srow) * K + sk0;
    for (int k0 = 0; k0 < K; k0 += 64) {
        *(bf16x8*)&As[srow][sk0 +  0] = *(const bf16x8*)(Ap + k0 +  0);
        *(bf16x8*)&As[srow][sk0 +  8] = *(const bf16x8*)(Ap + k0 +  8);
        *(bf16x8*)&As[srow][sk0 + 16] = *(const bf16x8*)(Ap + k0 + 16);
        *(bf16x8*)&As[srow][sk0 + 24] = *(const bf16x8*)(Ap + k0 + 24);
        *(bf16x8*)&Bs[srow][sk0 +  0] = *(const bf16x8*)(Bp + k0 +  0);
        *(bf16x8*)&Bs[srow][sk0 +  8] = *(const bf16x8*)(Bp + k0 +  8);
        *(bf16x8*)&Bs[srow][sk0 + 16] = *(const bf16x8*)(Bp + k0 + 16);
        *(bf16x8*)&Bs[srow][sk0 + 24] = *(const bf16x8*)(Bp + k0 + 24);
        __syncthreads();
        for (int ks = 0; ks < 2; ++ks) {
            bf16x8 af[4], bfr[4];
            for (int mt = 0; mt < 4; ++mt)
                af[mt]  = *(const bf16x8*)&As[wm + mt * 16 + l16][ks * 32 + quad * 8];
            for (int nt = 0; nt < 4; ++nt)
                bfr[nt] = *(const bf16x8*)&Bs[wn + nt * 16 + l16][ks * 32 + quad * 8];
            for (int mt = 0; mt < 4; ++mt)
                for (int nt = 0; nt < 4; ++nt)
                    acc[mt][nt] = __builtin_amdgcn_mfma_f32_16x16x32_bf16(af[mt], bfr[nt], acc[mt][nt], 0, 0, 0);
        }
        __syncthreads();
    }
    bool f32o = f32out && (*flag != 0);
    for (int mt = 0; mt < 4; ++mt)
        for (int nt = 0; nt < 4; ++nt) {
            int rowb = bm * 128 + wm + mt * 16 + quad * 4;
            int col  = bn * 128 + wn + nt * 16 + l16;
            if (f32o) {
                for (int r = 0; r < 4; ++r)
                    ((float*)C)[(size_t)(rowb + r) * N + col] = acc[mt][nt][r];
            } else {
                for (int r = 0; r < 4; ++r)
                    ((__bf16*)C)[(size_t)(rowb + r) * N + col] = (__bf16)acc[mt][nt][r];
            }
        }
}

// =====================================================================
// Split-bf16 f32-fidelity GEMM: C_f32[M][N] = A[M][K] @ B[K][N].
// A, B read directly (f32 or bf16 per flag); B staged transposed in LDS.
// 3-term MFMA (hh + hl + lh) -> ~1e-5 relative fidelity. Selection path.
// =====================================================================
__global__ __launch_bounds__(256) void gemm_split_f32_k(const void* __restrict__ A,
                                                        const void* __restrict__ B,
                                                        float* __restrict__ C,
                                                        int M, int N, int K,
                                                        const int* __restrict__ flag) {
    bool f = (*flag != 0);
    int bm = blockIdx.x, bn = blockIdx.y;
    __shared__ float Asf[128][36];
    __shared__ float Bsf[128][36];
    int tid = threadIdx.x, wave = tid >> 6, lane = tid & 63;
    int quad = lane >> 4, l16 = lane & 15;
    int wm = (wave >> 1) * 64, wn = (wave & 1) * 64;
    const f32x4 z4 = {0.f, 0.f, 0.f, 0.f};
    f32x4 acc[4][4];
    for (int a = 0; a < 4; ++a) for (int b = 0; b < 4; ++b) acc[a][b] = z4;
    int arow = tid >> 1, acol = (tid & 1) * 16;
    for (int k0 = 0; k0 < K; k0 += 32) {
        for (int g = 0; g < 4; ++g) {
            f32x4 v = load4(A, (size_t)(bm * 128 + arow) * K + k0 + acol + g * 4, f);
            *(f32x4*)&Asf[arow][acol + g * 4] = v;
        }
        for (int it = 0; it < 4; ++it) {
            int g = tid + it * 256;
            int krow = g >> 5, ng = (g & 31) * 4;
            f32x4 v = load4(B, (size_t)(k0 + krow) * N + bn * 128 + ng, f);
            Bsf[ng + 0][krow] = v[0];
            Bsf[ng + 1][krow] = v[1];
            Bsf[ng + 2][krow] = v[2];
            Bsf[ng + 3][krow] = v[3];
        }
        __syncthreads();
        bf16x8 ah[4], al[4], bh[4], bl[4];
        for (int mt = 0; mt < 4; ++mt) split8(&Asf[wm + mt * 16 + l16][quad * 8], ah[mt], al[mt]);
        for (int nt = 0; nt < 4; ++nt) split8(&Bsf[wn + nt * 16 + l16][quad * 8], bh[nt], bl[nt]);
        for (int mt = 0; mt < 4; ++mt)
            for (int nt = 0; nt < 4; ++nt) {
                acc[mt][nt] = __builtin_amdgcn_mfma_f32_16x16x32_bf16(al[mt], bh[nt], acc[mt][nt], 0, 0, 0);
                acc[mt][nt] = __builtin_amdgcn_mfma_f32_16x16x32_bf16(ah[mt], bl[nt], acc[mt][nt], 0, 0, 0);
                acc[mt][nt] = __builtin_amdgcn_mfma_f32_16x16x32_bf16(ah[mt], bh[nt], acc[mt][nt], 0, 0, 0);
            }
        __syncthreads();
    }
    for (int mt = 0; mt < 4; ++mt)
        for (int nt = 0; nt < 4; ++nt)
            for (int r = 0; r < 4; ++r)
                C[(size_t)(bm * 128 + wm + mt * 16 + quad * 4 + r) * N + bn * 128 + wn + nt * 16 + l16] = acc[mt][nt][r];
}

// =====================================================================
// RoPE in place on Qb (bf16, S x 2048). One thread per (pos, head, pair).
// =====================================================================
__global__ __launch_bounds__(256) void rope_k(__bf16* __restrict__ Qb,
                                              const void* __restrict__ fc,
                                              const void* __restrict__ fs,
                                              const int* __restrict__ flag) {
    int idx = blockIdx.x * 256 + threadIdx.x;   // SEQ*NH*32 = 4194304 threads
    int t = idx >> 10;
    int r = idx & 1023;
    int j = r & 31;
    __bf16* p = Qb + (size_t)t * DIMM + (r >> 5) * HD + 2 * j;
    float c, s;
    if (*flag) {
        c = ((const float*)fc)[t * 32 + j];
        s = ((const float*)fs)[t * 32 + j];
    } else {
        c = (float)((const __bf16*)fc)[t * 32 + j];
        s = (float)((const __bf16*)fs)[t * 32 + j];
    }
    float xr = (float)p[0], xi = (float)p[1];
    p[0] = (__bf16)(xr * c - xi * s);
    p[1] = (__bf16)(xr * s + xi * c);
}

// =====================================================================
// RoPE in place (f32) on Kf32 (S x 512) and Qef32 (first 64 rows x 2048).
// =====================================================================
__global__ __launch_bounds__(256) void rope_f32_k(float* __restrict__ Kf,
                                                  float* __restrict__ Qe,
                                                  const void* __restrict__ fc,
                                                  const void* __restrict__ fs,
                                                  const int* __restrict__ flag) {
    int idx = blockIdx.x * 256 + threadIdx.x;
    const int NKP = SEQ * NKV * 32;   // 1048576
    const int NQP = 64 * NH * 32;     // 65536
    float* p; int t, j;
    if (idx < NKP) {
        t = idx >> 8; int r = idx & 255; j = r & 31;
        p = Kf + (size_t)t * (NKV * HD) + (r >> 5) * HD + 2 * j;
    } else {
        int k = idx - NKP;
        if (k >= NQP) return;
        t = k >> 10; int r = k & 1023; j = r & 31;
        p = Qe + (size_t)t * DIMM + (r >> 5) * HD + 2 * j;
    }
    float c, s;
    if (*flag) {
        c = ((const float*)fc)[t * 32 + j];
        s = ((const float*)fs)[t * 32 + j];
    } else {
        c = (float)((const __bf16*)fc)[t * 32 + j];
        s = (float)((const __bf16*)fs)[t * 32 + j];
    }
    float xr = p[0], xi = p[1];
    p[0] = xr * c - xi * s;
    p[1] = xr * s + xi * c;
}

// =====================================================================
// Kf32 (post-rope) -> Kb bf16 for the sparse-attention value path.
// =====================================================================
__global__ __launch_bounds__(256) void kf_to_bf16_k(const float* __restrict__ Kf,
                                                    __bf16* __restrict__ Kb) {
    int i0 = (blockIdx.x * 256 + threadIdx.x) * 8;
    bf16x8 o;
    for (int i = 0; i < 8; ++i) o[i] = (__bf16)Kf[i0 + i];
    *(bf16x8*)(Kb + i0) = o;
}

// =====================================================================
// Estimation row stats from f32 Q/K via on-the-fly split (3-term MFMA).
// grid = 32 heads. Pass A: row max. Pass B: row sum of exp(l - max).
// =====================================================================
__global__ __launch_bounds__(256) void est_stats_k(const float* __restrict__ Qe,
                                                   const float* __restrict__ Kf,
                                                   float* __restrict__ rmax,
                                                   float* __restrict__ rsum) {
    int h = blockIdx.x;
    int tid = threadIdx.x, wave = tid >> 6, lane = tid & 63;
    int quad = lane >> 4, l16 = lane & 15;
    __shared__ float Ml[64];
    __shared__ float pA[4][64];
    bf16x8 qh[4][2], ql[4][2];
    for (int mt = 0; mt < 4; ++mt)
        for (int kc = 0; kc < 2; ++kc)
            split8(Qe + (size_t)(mt * 16 + l16) * DIMM + h * HD + kc * 32 + quad * 8,
                   qh[mt][kc], ql[mt][kc]);
    int kvoff = (h >> 2) * HD;
    // ---- pass A: row max ----
    float pmax[4][4];
    for (int mt = 0; mt < 4; ++mt) for (int r = 0; r < 4; ++r) pmax[mt][r] = -3.0e38f;
    for (int jb = wave; jb < 64; jb += 4)
        for (int c = 0; c < 4; ++c) {
            int j0 = jb * 64 + c * 16;
            const float* kp = Kf + (size_t)(j0 + l16) * (NKV * HD) + kvoff + quad * 8;
            bf16x8 kh0, kl0, kh1, kl1;
            split8(kp, kh0, kl0);
            split8(kp + 32, kh1, kl1);
            int j = j0 + l16;
            for (int mt = 0; mt < 4; ++mt) {
                f32x4 acc = {0.f, 0.f, 0.f, 0.f};
                acc = __builtin_amdgcn_mfma_f32_16x16x32_bf16(ql[mt][0], kh0, acc, 0, 0, 0);
                acc = __builtin_amdgcn_mfma_f32_16x16x32_bf16(qh[mt][0], kl0, acc, 0, 0, 0);
                acc = __builtin_amdgcn_mfma_f32_16x16x32_bf16(qh[mt][0], kh0, acc, 0, 0, 0);
                acc = __builtin_amdgcn_mfma_f32_16x16x32_bf16(ql[mt][1], kh1, acc, 0, 0, 0);
                acc = __builtin_amdgcn_mfma_f32_16x16x32_bf16(qh[mt][1], kl1, acc, 0, 0, 0);
                acc = __builtin_amdgcn_mfma_f32_16x16x32_bf16(qh[mt][1], kh1, acc, 0, 0, 0);
                for (int r = 0; r < 4; ++r) {
                    int q = mt * 16 + quad * 4 + r;
                    float sv = acc[r] * 0.125f;
                    if (j >= SEQ - 64 && q < j - (SEQ - 64)) sv = -1e30f;
                    pmax[mt][r] = fmaxf(pmax[mt][r], sv);
                }
            }
        }
    for (int mt = 0; mt < 4; ++mt)
        for (int r = 0; r < 4; ++r)
            for (int m2 = 1; m2 < 16; m2 <<= 1)
                pmax[mt][r] = fmaxf(pmax[mt][r], __shfl_xor(pmax[mt][r], m2));
    if (l16 == 0)
        for (int mt = 0; mt < 4; ++mt)
            for (int r = 0; r < 4; ++r)
                pA[wave][mt * 16 + quad * 4 + r] = pmax[mt][r];
    __syncthreads();
    if (tid < 64)
        Ml[tid] = fmaxf(fmaxf(pA[0][tid], pA[1][tid]), fmaxf(pA[2][tid], pA[3][tid]));
    __syncthreads();
    float mreg[4][4];
    for (int mt = 0; mt < 4; ++mt)
        for (int r = 0; r < 4; ++r)
            mreg[mt][r] = Ml[mt * 16 + quad * 4 + r];
    // ---- pass B: row sum ----
    float psum[4][4];
    for (int mt = 0; mt < 4; ++mt) for (int r = 0; r < 4; ++r) psum[mt][r] = 0.f;
    for (int jb = wave; jb < 64; jb += 4)
        for (int c = 0; c < 4; ++c) {
            int j0 = jb * 64 + c * 16;
            const float* kp = Kf + (size_t)(j0 + l16) * (NKV * HD) + kvoff + quad * 8;
            bf16x8 kh0, kl0, kh1, kl1;
            split8(kp, kh0, kl0);
            split8(kp + 32, kh1, kl1);
            int j = j0 + l16;
            for (int mt = 0; mt < 4; ++mt) {
                f32x4 acc = {0.f, 0.f, 0.f, 0.f};
                acc = __builtin_amdgcn_mfma_f32_16x16x32_bf16(ql[mt][0], kh0, acc, 0, 0, 0);
                acc = __builtin_amdgcn_mfma_f32_16x16x32_bf16(qh[mt][0], kl0, acc, 0, 0, 0);
                acc = __builtin_amdgcn_mfma_f32_16x16x32_bf16(qh[mt][0], kh0, acc, 0, 0, 0);
                acc = __builtin_amdgcn_mfma_f32_16x16x32_bf16(ql[mt][1], kh1, acc, 0, 0, 0);
                acc = __builtin_amdgcn_mfma_f32_16x16x32_bf16(qh[mt][1], kl1, acc, 0, 0, 0);
                acc = __builtin_amdgcn_mfma_f32_16x16x32_bf16(qh[mt][1], kh1, acc, 0, 0, 0);
                for (int r = 0; r < 4; ++r) {
                    int q = mt * 16 + quad * 4 + r;
                    float sv = acc[r] * 0.125f;
                    if (j >= SEQ - 64 && q < j - (SEQ - 64)) sv = -1e30f;
                    psum[mt][r] += __expf(sv - mreg[mt][r]);
                }
            }
        }
    for (int mt = 0; mt < 4; ++mt)
        for (int r = 0; r < 4; ++r)
            for (int m2 = 1; m2 < 16; m2 <<= 1)
                psum[mt][r] += __shfl_xor(psum[mt][r], m2);
    if (l16 == 0)
        for (int mt = 0; mt < 4; ++mt)
            for (int r = 0; r < 4; ++r)
                pA[wave][mt * 16 + quad * 4 + r] = psum[mt][r];
    __syncthreads();
    if (tid < 64) {
        rmax[h * 64 + tid] = Ml[tid];
        rsum[h * 64 + tid] = pA[0][tid] + pA[1][tid] + pA[2][tid] + pA[3][tid];
    }
}

__global__ __launch_bounds__(256) void zerof_k(float* __restrict__ p, int n) {
    int i = blockIdx.x * 256 + threadIdx.x;
    if (i < n) p[i] = 0.f;
}

// =====================================================================
// vertical[h][j] = sum_q probs; diag[h][g] += sum_q probs[q][g+q-63]
// grid (32 heads, 32 key-chunks of 128). f32-fidelity logits via split.
// =====================================================================
__global__ __launch_bounds__(256) void vert_diag_k(const float* __restrict__ Qe,
                                                   const float* __restrict__ Kf,
                                                   const float* __restrict__ rmax,
                                                   const float* __restrict__ rsum,
                                                   float* __restrict__ vert,
                                                   float* __restrict__ diag) {
    int h = blockIdx.x, jb = blockIdx.y;
    int tid = threadIdx.x, wave = tid >> 6, lane = tid & 63;
    int quad = lane >> 4, l16 = lane & 15;
    __shared__ float P[64][132];
    __shared__ float dloc[192];
    for (int i = tid; i < 192; i += 256) dloc[i] = 0.f;
    bf16x8 qh[4][2], ql[4][2];
    for (int mt = 0; mt < 4; ++mt)
        for (int kc = 0; kc < 2; ++kc)
            split8(Qe + (size_t)(mt * 16 + l16) * DIMM + h * HD + kc * 32 + quad * 8,
                   qh[mt][kc], ql[mt][kc]);
    float rm[4][4], rs[4][4];
    for (int mt = 0; mt < 4; ++mt)
        for (int r = 0; r < 4; ++r) {
            int q = mt * 16 + quad * 4 + r;
            rm[mt][r] = rmax[h * 64 + q];
            rs[mt][r] = rsum[h * 64 + q];
        }
    int kvoff = (h >> 2) * HD;
    for (int c = 0; c < 2; ++c) {
        int jl0 = wave * 32 + c * 16;
        int j0 = jb * 128 + jl0;
        const float* kp = Kf + (size_t)(j0 + l16) * (NKV * HD) + kvoff + quad * 8;
        bf16x8 kh0, kl0, kh1, kl1;
        split8(kp, kh0, kl0);
        split8(kp + 32, kh1, kl1);
        int j = j0 + l16;
        for (int mt = 0; mt < 4; ++mt) {
            f32x4 acc = {0.f, 0.f, 0.f, 0.f};
            acc = __builtin_amdgcn_mfma_f32_16x16x32_bf16(ql[mt][0], kh0, acc, 0, 0, 0);
            acc = __builtin_amdgcn_mfma_f32_16x16x32_bf16(qh[mt][0], kl0, acc, 0, 0, 0);
            acc = __builtin_amdgcn_mfma_f32_16x16x32_bf16(qh[mt][0], kh0, acc, 0, 0, 0);
            acc = __builtin_amdgcn_mfma_f32_16x16x32_bf16(ql[mt][1], kh1, acc, 0, 0, 0);
            acc = __builtin_amdgcn_mfma_f32_16x16x32_bf16(qh[mt][1], kl1, acc, 0, 0, 0);
            acc = __builtin_amdgcn_mfma_f32_16x16x32_bf16(qh[mt][1], kh1, acc, 0, 0, 0);
            for (int r = 0; r < 4; ++r) {
                int q = mt * 16 + quad * 4 + r;
                float sv = acc[r] * 0.125f;
                if (j >= SEQ - 64 && q < j - (SEQ - 64)) sv = -1e30f;
                P[q][jl0 + l16] = __expf(sv - rm[mt][r]) / rs[mt][r];
            }
        }
    }
    __syncthreads();
    if (tid < 128) {
        float vacc = 0.f;
        for (int q = 0; q < 64; ++q) {
            float pb = P[q][tid];
            vacc += pb;
            if (jb * 128 + tid + 63 - q < SEQ) atomicAdd(&dloc[tid + 63 - q], pb);
        }
        vert[h * SEQ + jb * 128 + tid] = vacc;
    }
    __syncthreads();
    for (int i = tid; i < 192; i += 256) {
        int g = jb * 128 + i;
        if (g < SEQ) atomicAdd(&diag[h * SEQ + g], dloc[i]);
    }
}

// =====================================================================
// Per-head: top-300 vertical + top-800 diag (slash=4095-g), merge, sort.
// jax tie-break (lowest index first) via (bits<<32)|(4095-idx) desc.
// =====================================================================
__device__ void bsort_u64_desc(unsigned long long* a, int n) {
    int tid = threadIdx.x;
    for (int k = 2; k <= n; k <<= 1)
        for (int j = k >> 1; j > 0; j >>= 1) {
            for (int i = tid; i < n; i += 256) {
                int ixj = i ^ j;
                if (ixj > i) {
                    unsigned long long x = a[i], y = a[ixj];
                    bool up = ((i & k) == 0);
                    if (up ? (x < y) : (x > y)) { a[i] = y; a[ixj] = x; }
                }
            }
            __syncthreads();
        }
}
__device__ void bsort_i32_asc(int* a, int n) {
    int tid = threadIdx.x;
    for (int k = 2; k <= n; k <<= 1)
        for (int j = k >> 1; j > 0; j >>= 1) {
            for (int i = tid; i < n; i += 256) {
                int ixj = i ^ j;
                if (ixj > i) {
                    int x = a[i], y = a[ixj];
                    bool up = ((i & k) == 0);
                    if (up ? (x > y) : (x < y)) { a[i] = y; a[ixj] = x; }
                }
            }
            __syncthreads();
        }
}
__global__ __launch_bounds__(256) void topk_merge_k(const float* __restrict__ vert,
                                                    const float* __restrict__ diag,
                                                    int* __restrict__ skeys) {
    __shared__ unsigned long long a[4096];
    __shared__ int sel[2048];
    int h = blockIdx.x, tid = threadIdx.x;
    for (int i = tid; i < 4096; i += 256) {
        unsigned int vb = __float_as_uint(vert[h * SEQ + i]);   // all values > 0
        a[i] = ((unsigned long long)vb << 32) | (unsigned)(4095 - i);
    }
    __syncthreads();
    bsort_u64_desc(a, 4096);
    for (int i = tid; i < 300; i += 256) sel[i] = 4095 - (int)(a[i] & 0xffffffffULL);
    __syncthreads();
    for (int i = tid; i < 4096; i += 256) {
        unsigned int vb = __float_as_uint(diag[h * SEQ + i]);
        a[i] = ((unsigned long long)vb << 32) | (unsigned)(4095 - i);
    }
    __syncthreads();
    bsort_u64_desc(a, 4096);
    // slash = 4095 - g = stored low word
    for (int i = tid; i < 800; i += 256) sel[300 + i] = (int)(a[i] & 0xffffffffULL);
    for (int i = tid; i < 948; i += 256) sel[1100 + i] = 0x7fffffff;
    __syncthreads();
    bsort_i32_asc(sel, 2048);
    for (int i = tid; i < NSPP; i += 256)
        skeys[h * NSPP + i] = (i < NSP) ? sel[i] : 0x7fffffff;
}

// =====================================================================
// Gather sparse K (keys x 64) and V transposed (64 x keys). Pads zeroed.
// =====================================================================
__global__ __launch_bounds__(256) void gather_k(const __bf16* __restrict__ Kb,
                                                const __bf16* __restrict__ Vb,
                                                const int* __restrict__ skeys,
                                                __bf16* __restrict__ Ksp,
                                                __bf16* __restrict__ VspT) {
    int idx = blockIdx.x * 256 + threadIdx.x;
    if (idx >= NH * NSPP) return;
    int h = idx / NSPP, j = idx % NSPP;
    int t = skeys[idx];
    int kv = (h >> 2) * HD;
    __bf16* kd = Ksp + (size_t)idx * HD;
    __bf16* vt = VspT + (size_t)h * HD * NSPP + j;
    if ((unsigned)t < SEQ) {
        const __bf16* ks = Kb + (size_t)t * (NKV * HD) + kv;
        const __bf16* vs = Vb + (size_t)t * (NKV * HD) + kv;
        for (int d = 0; d < HD; ++d) { kd[d] = ks[d]; vt[(size_t)d * NSPP] = vs[d]; }
    } else {
        for (int d = 0; d < HD; ++d) { kd[d] = (__bf16)0.f; vt[(size_t)d * NSPP] = (__bf16)0.f; }
    }
}

// =====================================================================
// Sparse attention: grid (32 heads, 256 q-tiles of 16). 4 waves.
// =====================================================================
__global__ __launch_bounds__(256) void sparse_attn_k(const __bf16* __restrict__ Qb,
                                                     const __bf16* __restrict__ Ksp,
                                                     const __bf16* __restrict__ VspT,
                                                     const int* __restrict__ skeys,
                                                     __bf16* __restrict__ AO) {
    int h = blockIdx.x, qb = blockIdx.y;
    int tid = threadIdx.x, wave = tid >> 6, lane = tid & 63;
    int quad = lane >> 4, l16 = lane & 15;
    __shared__ __bf16 sc[16][1160];     // logits then P, padded stride
    __shared__ float obuf[16][64];
    __shared__ float red[16][16];
    __shared__ float rmx[16], rsm[16];
    int t0 = qb * 16;
    bf16x8 aq0 = *(const bf16x8*)(Qb + (size_t)(t0 + l16) * DIMM + h * HD + quad * 8);
    bf16x8 aq1 = *(const bf16x8*)(Qb + (size_t)(t0 + l16) * DIMM + h * HD + 32 + quad * 8);
    const __bf16* Kh = Ksp + (size_t)h * NSPP * HD;
    const int* sk = skeys + h * NSPP;
    // ---- phase 1: QK^T ----
    for (int c = 0; c < 18; ++c) {
        int j0 = wave * 288 + c * 16;
        const __bf16* kp = Kh + (size_t)(j0 + l16) * HD + quad * 8;
        bf16x8 b0 = *(const bf16x8*)kp;
        bf16x8 b1 = *(const bf16x8*)(kp + 32);
        f32x4 acc = {0.f, 0.f, 0.f, 0.f};
        acc = __builtin_amdgcn_mfma_f32_16x16x32_bf16(aq0, b0, acc, 0, 0, 0);
        acc = __builtin_amdgcn_mfma_f32_16x16x32_bf16(aq1, b1, acc, 0, 0, 0);
        int j = j0 + l16;
        int key = sk[j];
        for (int r = 0; r < 4; ++r) {
            int q = quad * 4 + r;
            float sv = acc[r] * 0.125f;
            if (key > t0 + q) sv = -1e30f;         // causal, matches reference
            sc[q][j] = (__bf16)sv;                 // pads overwritten in phase 2
        }
    }
    __syncthreads();
    // ---- phase 2: softmax over 1100 real cols, 16 threads per row ----
    int row = tid >> 4, cg = tid & 15;
    float mx = -3.0e38f;
    for (int i = cg; i < NSP; i += 16) mx = fmaxf(mx, (float)sc[row][i]);
    red[row][cg] = mx;
    __syncthreads();
    if (cg == 0) {
        float m0 = red[row][0];
        for (int i = 1; i < 16; ++i) m0 = fmaxf(m0, red[row][i]);
        rmx[row] = m0;
    }
    __syncthreads();
    float m = rmx[row];
    float sm = 0.f;
    for (int i = cg; i < NSPP; i += 16) {
        float pv = 0.f;
        if (i < NSP) { pv = __expf((float)sc[row][i] - m); sm += pv; }
        sc[row][i] = (__bf16)pv;
    }
    red[row][cg] = sm;
    for (int i = tid; i < 16 * 64; i += 256) (&obuf[0][0])[i] = 0.f;
    __syncthreads();
    if (cg == 0) {
        float s2 = 0.f;
        for (int i = 0; i < 16; ++i) s2 += red[row][i];
        rsm[row] = s2;
    }
    // ---- phase 3: PV ----
    const f32x4 z4 = {0.f, 0.f, 0.f, 0.f};
    f32x4 oacc[4] = {z4, z4, z4, z4};
    for (int c = 0; c < 9; ++c) {
        int kb = wave * 288 + c * 32;
        bf16x8 af = *(const bf16x8*)&sc[l16][kb + quad * 8];
        for (int nt = 0; nt < 4; ++nt) {
            bf16x8 bv = *(const bf16x8*)(VspT + ((size_t)h * HD + nt * 16 + l16) * NSPP + kb + quad * 8);
            oacc[nt] = __builtin_amdgcn_mfma_f32_16x16x32_bf16(af, bv, oacc[nt], 0, 0, 0);
        }
    }
    for (int nt = 0; nt < 4; ++nt)
        for (int r = 0; r < 4; ++r)
            atomicAdd(&obuf[quad * 4 + r][nt * 16 + l16], oacc[nt][r]);
    __syncthreads();
    for (int i = tid; i < 1024; i += 256) {
        int q = i >> 6, d = i & 63;
        AO[(size_t)(t0 + q) * DIMM + h * HD + d] = (__bf16)(obuf[q][d] / rsm[q]);
    }
}

// =====================================================================
// Launch. Workspace (~50.2 MiB):
//  0        Qb bf16 16.8M
//  16.8M    Kb bf16 4.2M
//  21.0M    Vb bf16 4.2M
//  25.2M    UNION1 16.8M: {xbf} -> {Kf32 8.4M + Qef32 1M} -> {AO}
//  41.9M    UNION2 9.4M: {Wt 8.4M} <-> {Ksp 4.7M + VspT 4.7M}
//  51.4M    rmax/rsum/vert/diag/skeys/flag  (ends ~52.6M)
// =====================================================================
extern "C" void kernel_launch(void* const* d_in, const int* in_sizes, int n_in,
                              void* d_out, int out_size, void* d_ws, size_t ws_size,
                              hipStream_t stream) {
    const void* x  = d_in[0];
    const void* fc = d_in[1];
    const void* fs = d_in[2];
    const void* wq = d_in[3];
    const void* wk = d_in[4];
    const void* wv = d_in[5];
    const void* wo = d_in[6];
    char* ws = (char*)d_ws;

    __bf16* Qb   = (__bf16*)(ws + 0);
    __bf16* Kb   = (__bf16*)(ws + 16777216);
    __bf16* Vb   = (__bf16*)(ws + 20971520);
    __bf16* xbf  = (__bf16*)(ws + 25165824);   // UNION1
    float*  Kf32 = (float*)(ws + 25165824);    // after xbf dead
    float*  Qef32= (float*)(ws + 33554432);
    __bf16* AO   = (__bf16*)(ws + 25165824);   // after Kf32/Qef32 dead
    __bf16* Wt   = (__bf16*)(ws + 41943040);   // UNION2
    __bf16* Ksp  = (__bf16*)(ws + 41943040);
    __bf16* VspT = (__bf16*)(ws + 46661632);
    float*  rmax = (float*)(ws + 51380224);
    float*  rsum = (float*)(ws + 51388416);
    float*  vert = (float*)(ws + 51396608);
    float*  diag = (float*)(ws + 51920896);
    int*    skeys= (int*)(ws + 52445184);
    int*    flag = (int*)(ws + 52592640);

    dim3 b256(256);
    detect_k<<<1, b256, 0, stream>>>(x, flag);
    convert_x_k<<<4096, b256, 0, stream>>>(x, xbf, flag);
    // value-path projections (bf16)
    transpose_cvt_k<<<dim3(64, 64), b256, 0, stream>>>(wq, Wt, 2048, 2048, flag);
    gemm_nt_k<<<dim3(32, 16), b256, 0, stream>>>(xbf, Wt, Qb, 4096, 2048, 2048, 0, flag);
    transpose_cvt_k<<<dim3(16, 64), b256, 0, stream>>>(wv, Wt, 2048, 512, flag);
    gemm_nt_k<<<dim3(32, 4), b256, 0, stream>>>(xbf, Wt, Vb, 4096, 512, 2048, 0, flag);
    // selection-path projections (split-bf16 ~f32 fidelity); xbf dead now
    gemm_split_f32_k<<<dim3(32, 4), b256, 0, stream>>>(x, wk, Kf32, 4096, 512, 2048, flag);
    gemm_split_f32_k<<<dim3(1, 16), b256, 0, stream>>>(x, wq, Qef32, 128, 2048, 2048, flag);
    // rope
    rope_k<<<16384, b256, 0, stream>>>(Qb, fc, fs, flag);
    rope_f32_k<<<4352, b256, 0, stream>>>(Kf32, Qef32, fc, fs, flag);
    kf_to_bf16_k<<<1024, b256, 0, stream>>>(Kf32, Kb);
    // estimation (f32 fidelity)
    est_stats_k<<<32, b256, 0, stream>>>(Qef32, Kf32, rmax, rsum);
    zerof_k<<<512, b256, 0, stream>>>(diag, 32 * SEQ);
    vert_diag_k<<<dim3(32, 32), b256, 0, stream>>>(Qef32, Kf32, rmax, rsum, vert, diag);
    topk_merge_k<<<32, b256, 0, stream>>>(vert, diag, skeys);
    // sparse attention (bf16); Kf32/Qef32 dead -> AO may reuse UNION1
    gather_k<<<144, b256, 0, stream>>>(Kb, Vb, skeys, Ksp, VspT);
    sparse_attn_k<<<dim3(32, 256), b256, 0, stream>>>(Qb, Ksp, VspT, skeys, AO);
    // output projection (f32 store if inputs were f32)
    transpose_cvt_k<<<dim3(64, 64), b256, 0, stream>>>(wo, Wt, 2048, 2048, flag);
    gemm_nt_k<<<dim3(32, 16), b256, 0, stream>>>(AO, Wt, d_out, 4096, 2048, 2048, 1, flag);
}

// Round 5
// 1420.944 us; speedup vs baseline: 1.1984x; 1.1984x over previous
//
#include <hip/hip_runtime.h>
#include <hip/hip_bf16.h>
#include <math.h>
#include <stdint.h>

// ---- problem constants ----
#define SEQ   4096
#define DIMM  2048
#define NH    32
#define NKV   8
#define HD    64
#define NSP   1100   // 300 vertical + 800 slash (duplicates kept)
#define NSPP  1152   // padded to multiple of 64

typedef __bf16 bf16x8 __attribute__((ext_vector_type(8)));
typedef float  f32x4  __attribute__((ext_vector_type(4)));

// Split a run of 8 f32 into hi/lo bf16 fragments (hi+lo ~ f32 fidelity).
__device__ inline void split8(const float* __restrict__ p, bf16x8& h, bf16x8& l) {
#pragma unroll
    for (int i = 0; i < 8; ++i) {
        float v = p[i];
        __bf16 hv = (__bf16)v;
        h[i] = hv;
        l[i] = (__bf16)(v - (float)hv);
    }
}
// Load 4 consecutive elements as f32 from f32-or-bf16 memory.
__device__ inline f32x4 load4(const void* __restrict__ p, size_t idx, bool f) {
    if (f) return *(const f32x4*)((const float*)p + idx);
    const __bf16* b = (const __bf16*)p + idx;
    f32x4 v;
    v[0] = (float)b[0]; v[1] = (float)b[1]; v[2] = (float)b[2]; v[3] = (float)b[3];
    return v;
}

// =====================================================================
// Input-dtype detection: flag=1 -> f32 inputs/outputs, flag=0 -> bf16.
// =====================================================================
__global__ __launch_bounds__(256) void detect_k(const void* __restrict__ x,
                                                int* __restrict__ flag) {
    const __bf16* p = (const __bf16*)x;
    int tid = threadIdx.x;
    bool bad = false;
    for (int i = 0; i < 16; ++i) {
        float v = fabsf((float)p[tid * 16 + i]);
        if (!(v <= 1e10f)) bad = true;    // catches huge AND NaN
    }
    unsigned long long m = __ballot(bad);
    __shared__ unsigned long long w[4];
    if ((tid & 63) == 0) w[tid >> 6] = m;
    __syncthreads();
    if (tid == 0) flag[0] = ((w[0] | w[1] | w[2] | w[3]) != 0ULL) ? 1 : 0;
}

// =====================================================================
// Convert x to bf16, 8 elements/thread.
// =====================================================================
__global__ __launch_bounds__(256) void convert_x_k(const void* __restrict__ x,
                                                   __bf16* __restrict__ xb,
                                                   const int* __restrict__ flag) {
    int i0 = (blockIdx.x * 256 + threadIdx.x) * 8;
    if (*flag) {
        const float* xf = (const float*)x;
        bf16x8 o;
        for (int i = 0; i < 8; ++i) o[i] = (__bf16)xf[i0 + i];
        *(bf16x8*)(xb + i0) = o;
    } else {
        *(bf16x8*)(xb + i0) = *(const bf16x8*)((const __bf16*)x + i0);
    }
}

// =====================================================================
// Tile transpose + convert: out[c][r] = (bf16)in[r][c]
// =====================================================================
__global__ __launch_bounds__(256) void transpose_cvt_k(const void* __restrict__ in,
                                                       __bf16* __restrict__ out, int R, int C,
                                                       const int* __restrict__ flag) {
    __shared__ __bf16 tile[32][33];
    bool f = (*flag != 0);
    int cb = blockIdx.x * 32, rb = blockIdx.y * 32;
    int tx = threadIdx.x & 31, ty = threadIdx.x >> 5;   // 32 x 8
    for (int i = 0; i < 32; i += 8) {
        size_t idx = (size_t)(rb + ty + i) * C + cb + tx;
        float v = f ? ((const float*)in)[idx] : (float)((const __bf16*)in)[idx];
        tile[ty + i][tx] = (__bf16)v;
    }
    __syncthreads();
    for (int i = 0; i < 32; i += 8)
        out[(size_t)(cb + ty + i) * R + rb + tx] = tile[tx][ty + i];
}

// =====================================================================
// bf16 NT GEMM: C[M][N] = A[M][K] @ Bt[N][K]^T, f32 acc.
// =====================================================================
__global__ __launch_bounds__(256) void gemm_nt_k(const __bf16* __restrict__ A,
                                                 const __bf16* __restrict__ Bt,
                                                 void* __restrict__ C, int M, int N, int K,
                                                 int f32out, const int* __restrict__ flag) {
    int bm = blockIdx.x, bn = blockIdx.y;
    __shared__ __bf16 As[128][72];
    __shared__ __bf16 Bs[128][72];
    int tid = threadIdx.x, wave = tid >> 6, lane = tid & 63;
    int quad = lane >> 4, l16 = lane & 15;
    int wm = (wave >> 1) * 64, wn = (wave & 1) * 64;
    const f32x4 z4 = {0.f, 0.f, 0.f, 0.f};
    f32x4 acc[4][4];
    for (int a = 0; a < 4; ++a) for (int b = 0; b < 4; ++b) acc[a][b] = z4;
    int srow = tid >> 1, sk0 = (tid & 1) * 32;
    const __bf16* Ap = A  + (size_t)(bm * 128 + srow) * K + sk0;
    const __bf16* Bp = Bt + (size_t)(bn * 128 + srow) * K + sk0;
    for (int k0 = 0; k0 < K; k0 += 64) {
        *(bf16x8*)&As[srow][sk0 +  0] = *(const bf16x8*)(Ap + k0 +  0);
        *(bf16x8*)&As[srow][sk0 +  8] = *(const bf16x8*)(Ap + k0 +  8);
        *(bf16x8*)&As[srow][sk0 + 16] = *(const bf16x8*)(Ap + k0 + 16);
        *(bf16x8*)&As[srow][sk0 + 24] = *(const bf16x8*)(Ap + k0 + 24);
        *(bf16x8*)&Bs[srow][sk0 +  0] = *(const bf16x8*)(Bp + k0 +  0);
        *(bf16x8*)&Bs[srow][sk0 +  8] = *(const bf16x8*)(Bp + k0 +  8);
        *(bf16x8*)&Bs[srow][sk0 + 16] = *(const bf16x8*)(Bp + k0 + 16);
        *(bf16x8*)&Bs[srow][sk0 + 24] = *(const bf16x8*)(Bp + k0 + 24);
        __syncthreads();
        for (int ks = 0; ks < 2; ++ks) {
            bf16x8 af[4], bfr[4];
            for (int mt = 0; mt < 4; ++mt)
                af[mt]  = *(const bf16x8*)&As[wm + mt * 16 + l16][ks * 32 + quad * 8];
            for (int nt = 0; nt < 4; ++nt)
                bfr[nt] = *(const bf16x8*)&Bs[wn + nt * 16 + l16][ks * 32 + quad * 8];
            for (int mt = 0; mt < 4; ++mt)
                for (int nt = 0; nt < 4; ++nt)
                    acc[mt][nt] = __builtin_amdgcn_mfma_f32_16x16x32_bf16(af[mt], bfr[nt], acc[mt][nt], 0, 0, 0);
        }
        __syncthreads();
    }
    bool f32o = f32out && (*flag != 0);
    for (int mt = 0; mt < 4; ++mt)
        for (int nt = 0; nt < 4; ++nt) {
            int rowb = bm * 128 + wm + mt * 16 + quad * 4;
            int col  = bn * 128 + wn + nt * 16 + l16;
            if (f32o) {
                for (int r = 0; r < 4; ++r)
                    ((float*)C)[(size_t)(rowb + r) * N + col] = acc[mt][nt][r];
            } else {
                for (int r = 0; r < 4; ++r)
                    ((__bf16*)C)[(size_t)(rowb + r) * N + col] = (__bf16)acc[mt][nt][r];
            }
        }
}

// =====================================================================
// Split-bf16 f32-fidelity GEMM: C_f32[M][N] = A[M][K] @ B[K][N].
// =====================================================================
__global__ __launch_bounds__(256) void gemm_split_f32_k(const void* __restrict__ A,
                                                        const void* __restrict__ B,
                                                        float* __restrict__ C,
                                                        int M, int N, int K,
                                                        const int* __restrict__ flag) {
    bool f = (*flag != 0);
    int bm = blockIdx.x, bn = blockIdx.y;
    __shared__ float Asf[128][36];
    __shared__ float Bsf[128][36];
    int tid = threadIdx.x, wave = tid >> 6, lane = tid & 63;
    int quad = lane >> 4, l16 = lane & 15;
    int wm = (wave >> 1) * 64, wn = (wave & 1) * 64;
    const f32x4 z4 = {0.f, 0.f, 0.f, 0.f};
    f32x4 acc[4][4];
    for (int a = 0; a < 4; ++a) for (int b = 0; b < 4; ++b) acc[a][b] = z4;
    int arow = tid >> 1, acol = (tid & 1) * 16;
    for (int k0 = 0; k0 < K; k0 += 32) {
        for (int g = 0; g < 4; ++g) {
            f32x4 v = load4(A, (size_t)(bm * 128 + arow) * K + k0 + acol + g * 4, f);
            *(f32x4*)&Asf[arow][acol + g * 4] = v;
        }
        for (int it = 0; it < 4; ++it) {
            int g = tid + it * 256;
            int krow = g >> 5, ng = (g & 31) * 4;
            f32x4 v = load4(B, (size_t)(k0 + krow) * N + bn * 128 + ng, f);
            Bsf[ng + 0][krow] = v[0];
            Bsf[ng + 1][krow] = v[1];
            Bsf[ng + 2][krow] = v[2];
            Bsf[ng + 3][krow] = v[3];
        }
        __syncthreads();
        bf16x8 ah[4], al[4], bh[4], bl[4];
        for (int mt = 0; mt < 4; ++mt) split8(&Asf[wm + mt * 16 + l16][quad * 8], ah[mt], al[mt]);
        for (int nt = 0; nt < 4; ++nt) split8(&Bsf[wn + nt * 16 + l16][quad * 8], bh[nt], bl[nt]);
        for (int mt = 0; mt < 4; ++mt)
            for (int nt = 0; nt < 4; ++nt) {
                acc[mt][nt] = __builtin_amdgcn_mfma_f32_16x16x32_bf16(al[mt], bh[nt], acc[mt][nt], 0, 0, 0);
                acc[mt][nt] = __builtin_amdgcn_mfma_f32_16x16x32_bf16(ah[mt], bl[nt], acc[mt][nt], 0, 0, 0);
                acc[mt][nt] = __builtin_amdgcn_mfma_f32_16x16x32_bf16(ah[mt], bh[nt], acc[mt][nt], 0, 0, 0);
            }
        __syncthreads();
    }
    for (int mt = 0; mt < 4; ++mt)
        for (int nt = 0; nt < 4; ++nt)
            for (int r = 0; r < 4; ++r)
                C[(size_t)(bm * 128 + wm + mt * 16 + quad * 4 + r) * N + bn * 128 + wn + nt * 16 + l16] = acc[mt][nt][r];
}

// =====================================================================
// RoPE in place on Qb (bf16, S x 2048).
// =====================================================================
__global__ __launch_bounds__(256) void rope_k(__bf16* __restrict__ Qb,
                                              const void* __restrict__ fc,
                                              const void* __restrict__ fs,
                                              const int* __restrict__ flag) {
    int idx = blockIdx.x * 256 + threadIdx.x;   // SEQ*NH*32 = 4194304 threads
    int t = idx >> 10;
    int r = idx & 1023;
    int j = r & 31;
    __bf16* p = Qb + (size_t)t * DIMM + (r >> 5) * HD + 2 * j;
    float c, s;
    if (*flag) {
        c = ((const float*)fc)[t * 32 + j];
        s = ((const float*)fs)[t * 32 + j];
    } else {
        c = (float)((const __bf16*)fc)[t * 32 + j];
        s = (float)((const __bf16*)fs)[t * 32 + j];
    }
    float xr = (float)p[0], xi = (float)p[1];
    p[0] = (__bf16)(xr * c - xi * s);
    p[1] = (__bf16)(xr * s + xi * c);
}

// =====================================================================
// RoPE in place (f32) on Kf32 (S x 512) and Qef32 (first 64 rows x 2048).
// =====================================================================
__global__ __launch_bounds__(256) void rope_f32_k(float* __restrict__ Kf,
                                                  float* __restrict__ Qe,
                                                  const void* __restrict__ fc,
                                                  const void* __restrict__ fs,
                                                  const int* __restrict__ flag) {
    int idx = blockIdx.x * 256 + threadIdx.x;
    const int NKP = SEQ * NKV * 32;   // 1048576
    const int NQP = 64 * NH * 32;     // 65536
    float* p; int t, j;
    if (idx < NKP) {
        t = idx >> 8; int r = idx & 255; j = r & 31;
        p = Kf + (size_t)t * (NKV * HD) + (r >> 5) * HD + 2 * j;
    } else {
        int k = idx - NKP;
        if (k >= NQP) return;
        t = k >> 10; int r = k & 1023; j = r & 31;
        p = Qe + (size_t)t * DIMM + (r >> 5) * HD + 2 * j;
    }
    float c, s;
    if (*flag) {
        c = ((const float*)fc)[t * 32 + j];
        s = ((const float*)fs)[t * 32 + j];
    } else {
        c = (float)((const __bf16*)fc)[t * 32 + j];
        s = (float)((const __bf16*)fs)[t * 32 + j];
    }
    float xr = p[0], xi = p[1];
    p[0] = xr * c - xi * s;
    p[1] = xr * s + xi * c;
}

// =====================================================================
// Kf32 (post-rope) -> Kb bf16 for the sparse-attention value path.
// =====================================================================
__global__ __launch_bounds__(256) void kf_to_bf16_k(const float* __restrict__ Kf,
                                                    __bf16* __restrict__ Kb) {
    int i0 = (blockIdx.x * 256 + threadIdx.x) * 8;
    bf16x8 o;
    for (int i = 0; i < 8; ++i) o[i] = (__bf16)Kf[i0 + i];
    *(bf16x8*)(Kb + i0) = o;
}

// =====================================================================
// Estimation partial row stats over a 512-key slice. grid (32 heads, 8).
// Two passes (max, then sum of exp) at f32 fidelity via split MFMA.
// =====================================================================
__global__ __launch_bounds__(256) void est_part_k(const float* __restrict__ Qe,
                                                  const float* __restrict__ Kf,
                                                  float* __restrict__ pm,
                                                  float* __restrict__ ps) {
    int h = blockIdx.x, sl = blockIdx.y;
    int tid = threadIdx.x, wave = tid >> 6, lane = tid & 63;
    int quad = lane >> 4, l16 = lane & 15;
    __shared__ float Ml[64];
    __shared__ float pA[4][64];
    bf16x8 qh[4][2], ql[4][2];
    for (int mt = 0; mt < 4; ++mt)
        for (int kc = 0; kc < 2; ++kc)
            split8(Qe + (size_t)(mt * 16 + l16) * DIMM + h * HD + kc * 32 + quad * 8,
                   qh[mt][kc], ql[mt][kc]);
    int kvoff = (h >> 2) * HD;
    // ---- pass A: slice max ----
    float pmax[4][4];
    for (int mt = 0; mt < 4; ++mt) for (int r = 0; r < 4; ++r) pmax[mt][r] = -3.0e38f;
    for (int jb = wave; jb < 8; jb += 4)
        for (int c = 0; c < 4; ++c) {
            int j0 = sl * 512 + jb * 64 + c * 16;
            const float* kp = Kf + (size_t)(j0 + l16) * (NKV * HD) + kvoff + quad * 8;
            bf16x8 kh0, kl0, kh1, kl1;
            split8(kp, kh0, kl0);
            split8(kp + 32, kh1, kl1);
            int j = j0 + l16;
            for (int mt = 0; mt < 4; ++mt) {
                f32x4 acc = {0.f, 0.f, 0.f, 0.f};
                acc = __builtin_amdgcn_mfma_f32_16x16x32_bf16(ql[mt][0], kh0, acc, 0, 0, 0);
                acc = __builtin_amdgcn_mfma_f32_16x16x32_bf16(qh[mt][0], kl0, acc, 0, 0, 0);
                acc = __builtin_amdgcn_mfma_f32_16x16x32_bf16(qh[mt][0], kh0, acc, 0, 0, 0);
                acc = __builtin_amdgcn_mfma_f32_16x16x32_bf16(ql[mt][1], kh1, acc, 0, 0, 0);
                acc = __builtin_amdgcn_mfma_f32_16x16x32_bf16(qh[mt][1], kl1, acc, 0, 0, 0);
                acc = __builtin_amdgcn_mfma_f32_16x16x32_bf16(qh[mt][1], kh1, acc, 0, 0, 0);
                for (int r = 0; r < 4; ++r) {
                    int q = mt * 16 + quad * 4 + r;
                    float sv = acc[r] * 0.125f;
                    if (j >= SEQ - 64 && q < j - (SEQ - 64)) sv = -1e30f;
                    pmax[mt][r] = fmaxf(pmax[mt][r], sv);
                }
            }
        }
    for (int mt = 0; mt < 4; ++mt)
        for (int r = 0; r < 4; ++r)
            for (int m2 = 1; m2 < 16; m2 <<= 1)
                pmax[mt][r] = fmaxf(pmax[mt][r], __shfl_xor(pmax[mt][r], m2));
    if (l16 == 0)
        for (int mt = 0; mt < 4; ++mt)
            for (int r = 0; r < 4; ++r)
                pA[wave][mt * 16 + quad * 4 + r] = pmax[mt][r];
    __syncthreads();
    if (tid < 64)
        Ml[tid] = fmaxf(fmaxf(pA[0][tid], pA[1][tid]), fmaxf(pA[2][tid], pA[3][tid]));
    __syncthreads();
    float mreg[4][4];
    for (int mt = 0; mt < 4; ++mt)
        for (int r = 0; r < 4; ++r)
            mreg[mt][r] = Ml[mt * 16 + quad * 4 + r];
    // ---- pass B: slice sum ----
    float psum[4][4];
    for (int mt = 0; mt < 4; ++mt) for (int r = 0; r < 4; ++r) psum[mt][r] = 0.f;
    for (int jb = wave; jb < 8; jb += 4)
        for (int c = 0; c < 4; ++c) {
            int j0 = sl * 512 + jb * 64 + c * 16;
            const float* kp = Kf + (size_t)(j0 + l16) * (NKV * HD) + kvoff + quad * 8;
            bf16x8 kh0, kl0, kh1, kl1;
            split8(kp, kh0, kl0);
            split8(kp + 32, kh1, kl1);
            int j = j0 + l16;
            for (int mt = 0; mt < 4; ++mt) {
                f32x4 acc = {0.f, 0.f, 0.f, 0.f};
                acc = __builtin_amdgcn_mfma_f32_16x16x32_bf16(ql[mt][0], kh0, acc, 0, 0, 0);
                acc = __builtin_amdgcn_mfma_f32_16x16x32_bf16(qh[mt][0], kl0, acc, 0, 0, 0);
                acc = __builtin_amdgcn_mfma_f32_16x16x32_bf16(qh[mt][0], kh0, acc, 0, 0, 0);
                acc = __builtin_amdgcn_mfma_f32_16x16x32_bf16(ql[mt][1], kh1, acc, 0, 0, 0);
                acc = __builtin_amdgcn_mfma_f32_16x16x32_bf16(qh[mt][1], kl1, acc, 0, 0, 0);
                acc = __builtin_amdgcn_mfma_f32_16x16x32_bf16(qh[mt][1], kh1, acc, 0, 0, 0);
                for (int r = 0; r < 4; ++r) {
                    int q = mt * 16 + quad * 4 + r;
                    float sv = acc[r] * 0.125f;
                    if (j >= SEQ - 64 && q < j - (SEQ - 64)) sv = -1e30f;
                    psum[mt][r] += __expf(sv - mreg[mt][r]);
                }
            }
        }
    for (int mt = 0; mt < 4; ++mt)
        for (int r = 0; r < 4; ++r)
            for (int m2 = 1; m2 < 16; m2 <<= 1)
                psum[mt][r] += __shfl_xor(psum[mt][r], m2);
    if (l16 == 0)
        for (int mt = 0; mt < 4; ++mt)
            for (int r = 0; r < 4; ++r)
                pA[wave][mt * 16 + quad * 4 + r] = psum[mt][r];
    __syncthreads();
    if (tid < 64) {
        pm[(h * 8 + sl) * 64 + tid] = Ml[tid];
        ps[(h * 8 + sl) * 64 + tid] = pA[0][tid] + pA[1][tid] + pA[2][tid] + pA[3][tid];
    }
}

// Combine 8 slice partials -> rmax/rsum. grid 32, block 64.
__global__ __launch_bounds__(64) void est_comb_k(const float* __restrict__ pm,
                                                 const float* __restrict__ ps,
                                                 float* __restrict__ rmax,
                                                 float* __restrict__ rsum) {
    int h = blockIdx.x, q = threadIdx.x;
    float M = -3.0e38f;
    for (int sl = 0; sl < 8; ++sl) M = fmaxf(M, pm[(h * 8 + sl) * 64 + q]);
    float S = 0.f;
    for (int sl = 0; sl < 8; ++sl)
        S += ps[(h * 8 + sl) * 64 + q] * __expf(pm[(h * 8 + sl) * 64 + q] - M);
    rmax[h * 64 + q] = M;
    rsum[h * 64 + q] = S;
}

__global__ __launch_bounds__(256) void zerof_k(float* __restrict__ p, int n) {
    int i = blockIdx.x * 256 + threadIdx.x;
    if (i < n) p[i] = 0.f;
}

// =====================================================================
// vertical[h][j] = sum_q probs; diag[h][g] += sum_q probs[q][g+q-63]
// grid (32 heads, 32 key-chunks of 128). f32-fidelity logits via split.
// =====================================================================
__global__ __launch_bounds__(256) void vert_diag_k(const float* __restrict__ Qe,
                                                   const float* __restrict__ Kf,
                                                   const float* __restrict__ rmax,
                                                   const float* __restrict__ rsum,
                                                   float* __restrict__ vert,
                                                   float* __restrict__ diag) {
    int h = blockIdx.x, jb = blockIdx.y;
    int tid = threadIdx.x, wave = tid >> 6, lane = tid & 63;
    int quad = lane >> 4, l16 = lane & 15;
    __shared__ float P[64][132];
    __shared__ float dloc[192];
    for (int i = tid; i < 192; i += 256) dloc[i] = 0.f;
    bf16x8 qh[4][2], ql[4][2];
    for (int mt = 0; mt < 4; ++mt)
        for (int kc = 0; kc < 2; ++kc)
            split8(Qe + (size_t)(mt * 16 + l16) * DIMM + h * HD + kc * 32 + quad * 8,
                   qh[mt][kc], ql[mt][kc]);
    float rm[4][4], rs[4][4];
    for (int mt = 0; mt < 4; ++mt)
        for (int r = 0; r < 4; ++r) {
            int q = mt * 16 + quad * 4 + r;
            rm[mt][r] = rmax[h * 64 + q];
            rs[mt][r] = rsum[h * 64 + q];
        }
    int kvoff = (h >> 2) * HD;
    for (int c = 0; c < 2; ++c) {
        int jl0 = wave * 32 + c * 16;
        int j0 = jb * 128 + jl0;
        const float* kp = Kf + (size_t)(j0 + l16) * (NKV * HD) + kvoff + quad * 8;
        bf16x8 kh0, kl0, kh1, kl1;
        split8(kp, kh0, kl0);
        split8(kp + 32, kh1, kl1);
        int j = j0 + l16;
        for (int mt = 0; mt < 4; ++mt) {
            f32x4 acc = {0.f, 0.f, 0.f, 0.f};
            acc = __builtin_amdgcn_mfma_f32_16x16x32_bf16(ql[mt][0], kh0, acc, 0, 0, 0);
            acc = __builtin_amdgcn_mfma_f32_16x16x32_bf16(qh[mt][0], kl0, acc, 0, 0, 0);
            acc = __builtin_amdgcn_mfma_f32_16x16x32_bf16(qh[mt][0], kh0, acc, 0, 0, 0);
            acc = __builtin_amdgcn_mfma_f32_16x16x32_bf16(ql[mt][1], kh1, acc, 0, 0, 0);
            acc = __builtin_amdgcn_mfma_f32_16x16x32_bf16(qh[mt][1], kl1, acc, 0, 0, 0);
            acc = __builtin_amdgcn_mfma_f32_16x16x32_bf16(qh[mt][1], kh1, acc, 0, 0, 0);
            for (int r = 0; r < 4; ++r) {
                int q = mt * 16 + quad * 4 + r;
                float sv = acc[r] * 0.125f;
                if (j >= SEQ - 64 && q < j - (SEQ - 64)) sv = -1e30f;
                P[q][jl0 + l16] = __expf(sv - rm[mt][r]) / rs[mt][r];
            }
        }
    }
    __syncthreads();
    if (tid < 128) {
        float vacc = 0.f;
        for (int q = 0; q < 64; ++q) {
            float pb = P[q][tid];
            vacc += pb;
            if (jb * 128 + tid + 63 - q < SEQ) atomicAdd(&dloc[tid + 63 - q], pb);
        }
        vert[h * SEQ + jb * 128 + tid] = vacc;
    }
    __syncthreads();
    for (int i = tid; i < 192; i += 256) {
        int g = jb * 128 + i;
        if (g < SEQ) atomicAdd(&diag[h * SEQ + g], dloc[i]);
    }
}

// =====================================================================
// Per-head: top-300 vertical + top-800 diag (slash=4095-g), merge, sort.
// =====================================================================
__device__ void bsort_u64_desc(unsigned long long* a, int n) {
    int tid = threadIdx.x;
    for (int k = 2; k <= n; k <<= 1)
        for (int j = k >> 1; j > 0; j >>= 1) {
            for (int i = tid; i < n; i += 256) {
                int ixj = i ^ j;
                if (ixj > i) {
                    unsigned long long x = a[i], y = a[ixj];
                    bool up = ((i & k) == 0);
                    if (up ? (x < y) : (x > y)) { a[i] = y; a[ixj] = x; }
                }
            }
            __syncthreads();
        }
}
__device__ void bsort_i32_asc(int* a, int n) {
    int tid = threadIdx.x;
    for (int k = 2; k <= n; k <<= 1)
        for (int j = k >> 1; j > 0; j >>= 1) {
            for (int i = tid; i < n; i += 256) {
                int ixj = i ^ j;
                if (ixj > i) {
                    int x = a[i], y = a[ixj];
                    bool up = ((i & k) == 0);
                    if (up ? (x > y) : (x < y)) { a[i] = y; a[ixj] = x; }
                }
            }
            __syncthreads();
        }
}
__global__ __launch_bounds__(256) void topk_merge_k(const float* __restrict__ vert,
                                                    const float* __restrict__ diag,
                                                    int* __restrict__ skeys) {
    __shared__ unsigned long long a[4096];
    __shared__ int sel[2048];
    int h = blockIdx.x, tid = threadIdx.x;
    for (int i = tid; i < 4096; i += 256) {
        unsigned int vb = __float_as_uint(vert[h * SEQ + i]);   // all values > 0
        a[i] = ((unsigned long long)vb << 32) | (unsigned)(4095 - i);
    }
    __syncthreads();
    bsort_u64_desc(a, 4096);
    for (int i = tid; i < 300; i += 256) sel[i] = 4095 - (int)(a[i] & 0xffffffffULL);
    __syncthreads();
    for (int i = tid; i < 4096; i += 256) {
        unsigned int vb = __float_as_uint(diag[h * SEQ + i]);
        a[i] = ((unsigned long long)vb << 32) | (unsigned)(4095 - i);
    }
    __syncthreads();
    bsort_u64_desc(a, 4096);
    // slash = 4095 - g = stored low word
    for (int i = tid; i < 800; i += 256) sel[300 + i] = (int)(a[i] & 0xffffffffULL);
    for (int i = tid; i < 948; i += 256) sel[1100 + i] = 0x7fffffff;
    __syncthreads();
    bsort_i32_asc(sel, 2048);
    for (int i = tid; i < NSPP; i += 256)
        skeys[h * NSPP + i] = (i < NSP) ? sel[i] : 0x7fffffff;
}

// =====================================================================
// Gather sparse K (keys x 64) and V transposed (64 x keys). Pads zeroed.
// =====================================================================
__global__ __launch_bounds__(256) void gather_k(const __bf16* __restrict__ Kb,
                                                const __bf16* __restrict__ Vb,
                                                const int* __restrict__ skeys,
                                                __bf16* __restrict__ Ksp,
                                                __bf16* __restrict__ VspT) {
    int idx = blockIdx.x * 256 + threadIdx.x;
    if (idx >= NH * NSPP) return;
    int h = idx / NSPP, j = idx % NSPP;
    int t = skeys[idx];
    int kv = (h >> 2) * HD;
    __bf16* kd = Ksp + (size_t)idx * HD;
    __bf16* vt = VspT + (size_t)h * HD * NSPP + j;
    if ((unsigned)t < SEQ) {
        const __bf16* ks = Kb + (size_t)t * (NKV * HD) + kv;
        const __bf16* vs = Vb + (size_t)t * (NKV * HD) + kv;
        for (int d8 = 0; d8 < 8; ++d8)
            *(bf16x8*)(kd + d8 * 8) = *(const bf16x8*)(ks + d8 * 8);
        for (int d = 0; d < HD; ++d) vt[(size_t)d * NSPP] = vs[d];
    } else {
        const bf16x8 z = {};
        for (int d8 = 0; d8 < 8; ++d8) *(bf16x8*)(kd + d8 * 8) = z;
        for (int d = 0; d < HD; ++d) vt[(size_t)d * NSPP] = (__bf16)0.f;
    }
}

// =====================================================================
// Sparse attention: grid (128 q-tiles of 32, 32 heads). 4 waves/block.
// Phase 1: QK^T (K frags shared across 2 q-subtiles) -> bf16 logits in
//   LDS; pads masked via skeys=INT_MAX -> -1e30.
// Phase 2: vectorized softmax, 8 lanes/row, shfl reduce; pad cols P=0.
// Phase 3: atomic-free PV: wave owns (q-subtile, d-half) quarter.
// =====================================================================
__global__ __launch_bounds__(256) void sparse_attn_k(const __bf16* __restrict__ Qb,
                                                     const __bf16* __restrict__ Ksp,
                                                     const __bf16* __restrict__ VspT,
                                                     const int* __restrict__ skeys,
                                                     __bf16* __restrict__ AO) {
    int qb = blockIdx.x, h = blockIdx.y;
    int tid = threadIdx.x, wave = tid >> 6, lane = tid & 63;
    int quad = lane >> 4, l16 = lane & 15;
    __shared__ __bf16 sc[32][1160];     // logits then P; stride 1160 (bank-spread)
    __shared__ float rsm[32];
    int t0 = qb * 32;
    bf16x8 aq[2][2];
    for (int qs = 0; qs < 2; ++qs)
        for (int kc = 0; kc < 2; ++kc)
            aq[qs][kc] = *(const bf16x8*)(Qb + (size_t)(t0 + qs * 16 + l16) * DIMM + h * HD + kc * 32 + quad * 8);
    const __bf16* Kh = Ksp + (size_t)h * NSPP * HD;
    const int* sk = skeys + h * NSPP;
    // ---- phase 1: QK^T ----
    for (int c = 0; c < 18; ++c) {
        int j0 = wave * 288 + c * 16;
        const __bf16* kp = Kh + (size_t)(j0 + l16) * HD + quad * 8;
        bf16x8 b0 = *(const bf16x8*)kp;
        bf16x8 b1 = *(const bf16x8*)(kp + 32);
        int j = j0 + l16;
        int key = sk[j];                 // pads hold INT_MAX -> always masked
        for (int qs = 0; qs < 2; ++qs) {
            f32x4 acc = {0.f, 0.f, 0.f, 0.f};
            acc = __builtin_amdgcn_mfma_f32_16x16x32_bf16(aq[qs][0], b0, acc, 0, 0, 0);
            acc = __builtin_amdgcn_mfma_f32_16x16x32_bf16(aq[qs][1], b1, acc, 0, 0, 0);
            int qg = t0 + qs * 16 + quad * 4;
            for (int r = 0; r < 4; ++r) {
                float sv = acc[r] * 0.125f;
                if (key > qg + r) sv = -1e30f;     // causal (finite, matches ref)
                sc[qs * 16 + quad * 4 + r][j] = (__bf16)sv;
            }
        }
    }
    __syncthreads();
    // ---- phase 2: softmax; 8 lanes/row, 144 consecutive cols each ----
    {
        int row = tid >> 3, sub = tid & 7;
        int c0 = sub * 144;
        float mx = -3.0e38f;
        for (int i = 0; i < 18; ++i) {
            bf16x8 v = *(const bf16x8*)&sc[row][c0 + i * 8];
            for (int e = 0; e < 8; ++e) mx = fmaxf(mx, (float)v[e]);
        }
        for (int m2 = 1; m2 < 8; m2 <<= 1) mx = fmaxf(mx, __shfl_xor(mx, m2, 8));
        float sm = 0.f;
        for (int i = 0; i < 18; ++i) {
            int cb = c0 + i * 8;
            bf16x8 v = *(const bf16x8*)&sc[row][cb];
            bf16x8 pw;
            for (int e = 0; e < 8; ++e) {
                float pv = 0.f;
                if (cb + e < NSP) { pv = __expf((float)v[e] - mx); sm += pv; }
                pw[e] = (__bf16)pv;
            }
            *(bf16x8*)&sc[row][cb] = pw;
        }
        for (int m2 = 1; m2 < 8; m2 <<= 1) sm += __shfl_xor(sm, m2, 8);
        if (sub == 0) rsm[row] = sm;
    }
    __syncthreads();
    // ---- phase 3: PV; wave -> (q-subtile, d-half) ----
    int qs = wave >> 1, dh = wave & 1;
    const f32x4 z4 = {0.f, 0.f, 0.f, 0.f};
    f32x4 o0 = z4, o1 = z4;
    const __bf16* Vh = VspT + ((size_t)h * HD + dh * 32) * NSPP;
    for (int c = 0; c < 36; ++c) {
        int kb = c * 32;
        bf16x8 pa = *(const bf16x8*)&sc[qs * 16 + l16][kb + quad * 8];
        bf16x8 v0 = *(const bf16x8*)(Vh + (size_t)l16 * NSPP + kb + quad * 8);
        bf16x8 v1 = *(const bf16x8*)(Vh + (size_t)(16 + l16) * NSPP + kb + quad * 8);
        o0 = __builtin_amdgcn_mfma_f32_16x16x32_bf16(pa, v0, o0, 0, 0, 0);
        o1 = __builtin_amdgcn_mfma_f32_16x16x32_bf16(pa, v1, o1, 0, 0, 0);
    }
    for (int r = 0; r < 4; ++r) {
        int ql = qs * 16 + quad * 4 + r;
        float inv = 1.f / rsm[ql];
        size_t base = (size_t)(t0 + ql) * DIMM + h * HD + dh * 32;
        AO[base + l16]      = (__bf16)(o0[r] * inv);
        AO[base + 16 + l16] = (__bf16)(o1[r] * inv);
    }
}

// =====================================================================
// Launch. Workspace (~52.7 MiB):
//  0        Qb bf16 16.8M
//  16.8M    Kb bf16 4.2M | 21.0M Vb bf16 4.2M
//  25.2M    UNION1: {xbf 16.8M} -> {Kf32 8.4M + Qef32 1M} -> {AO 16.8M}
//  41.9M    UNION2: {Wt 8.4M} <-> {Ksp 4.7M + VspT 4.7M}
//  51.4M    rmax/rsum/vert/diag/skeys/flag/pm/ps
// =====================================================================
extern "C" void kernel_launch(void* const* d_in, const int* in_sizes, int n_in,
                              void* d_out, int out_size, void* d_ws, size_t ws_size,
                              hipStream_t stream) {
    const void* x  = d_in[0];
    const void* fc = d_in[1];
    const void* fs = d_in[2];
    const void* wq = d_in[3];
    const void* wk = d_in[4];
    const void* wv = d_in[5];
    const void* wo = d_in[6];
    char* ws = (char*)d_ws;

    __bf16* Qb   = (__bf16*)(ws + 0);
    __bf16* Kb   = (__bf16*)(ws + 16777216);
    __bf16* Vb   = (__bf16*)(ws + 20971520);
    __bf16* xbf  = (__bf16*)(ws + 25165824);   // UNION1
    float*  Kf32 = (float*)(ws + 25165824);    // after xbf dead
    float*  Qef32= (float*)(ws + 33554432);
    __bf16* AO   = (__bf16*)(ws + 25165824);   // after Kf32/Qef32 dead
    __bf16* Wt   = (__bf16*)(ws + 41943040);   // UNION2
    __bf16* Ksp  = (__bf16*)(ws + 41943040);
    __bf16* VspT = (__bf16*)(ws + 46661632);
    float*  rmax = (float*)(ws + 51380224);
    float*  rsum = (float*)(ws + 51388416);
    float*  vert = (float*)(ws + 51396608);
    float*  diag = (float*)(ws + 51920896);
    int*    skeys= (int*)(ws + 52445184);
    int*    flag = (int*)(ws + 52592640);
    float*  pm   = (float*)(ws + 52592896);
    float*  ps   = (float*)(ws + 52658432);

    dim3 b256(256);
    detect_k<<<1, b256, 0, stream>>>(x, flag);
    convert_x_k<<<4096, b256, 0, stream>>>(x, xbf, flag);
    // value-path projections (bf16)
    transpose_cvt_k<<<dim3(64, 64), b256, 0, stream>>>(wq, Wt, 2048, 2048, flag);
    gemm_nt_k<<<dim3(32, 16), b256, 0, stream>>>(xbf, Wt, Qb, 4096, 2048, 2048, 0, flag);
    transpose_cvt_k<<<dim3(16, 64), b256, 0, stream>>>(wv, Wt, 2048, 512, flag);
    gemm_nt_k<<<dim3(32, 4), b256, 0, stream>>>(xbf, Wt, Vb, 4096, 512, 2048, 0, flag);
    // selection-path projections (split-bf16 ~f32 fidelity); xbf dead now
    gemm_split_f32_k<<<dim3(32, 4), b256, 0, stream>>>(x, wk, Kf32, 4096, 512, 2048, flag);
    gemm_split_f32_k<<<dim3(1, 16), b256, 0, stream>>>(x, wq, Qef32, 128, 2048, 2048, flag);
    // rope
    rope_k<<<16384, b256, 0, stream>>>(Qb, fc, fs, flag);
    rope_f32_k<<<4352, b256, 0, stream>>>(Kf32, Qef32, fc, fs, flag);
    kf_to_bf16_k<<<1024, b256, 0, stream>>>(Kf32, Kb);
    // estimation (f32 fidelity), 256-block partial + combine
    est_part_k<<<dim3(32, 8), b256, 0, stream>>>(Qef32, Kf32, pm, ps);
    est_comb_k<<<32, dim3(64), 0, stream>>>(pm, ps, rmax, rsum);
    zerof_k<<<512, b256, 0, stream>>>(diag, 32 * SEQ);
    vert_diag_k<<<dim3(32, 32), b256, 0, stream>>>(Qef32, Kf32, rmax, rsum, vert, diag);
    topk_merge_k<<<32, b256, 0, stream>>>(vert, diag, skeys);
    // sparse attention (bf16); Kf32/Qef32 dead -> AO may reuse UNION1
    gather_k<<<144, b256, 0, stream>>>(Kb, Vb, skeys, Ksp, VspT);
    sparse_attn_k<<<dim3(128, 32), b256, 0, stream>>>(Qb, Ksp, VspT, skeys, AO);
    // output projection (f32 store if inputs were f32)
    transpose_cvt_k<<<dim3(64, 64), b256, 0, stream>>>(wo, Wt, 2048, 2048, flag);
    gemm_nt_k<<<dim3(32, 16), b256, 0, stream>>>(AO, Wt, d_out, 4096, 2048, 2048, 1, flag);
}

// Round 6
// 1115.369 us; speedup vs baseline: 1.5268x; 1.2740x over previous
//
#include <hip/hip_runtime.h>
#include <hip/hip_bf16.h>
#include <math.h>
#include <stdint.h>

// ---- problem constants ----
#define SEQ   4096
#define DIMM  2048
#define NH    32
#define NKV   8
#define HD    64
#define NSP   1100   // 300 vertical + 800 slash (duplicates kept)
#define NSPP  1152   // padded to multiple of 64

typedef __bf16 bf16x8 __attribute__((ext_vector_type(8)));
typedef float  f32x4  __attribute__((ext_vector_type(4)));

// Split a run of 8 f32 into hi/lo bf16 fragments (hi+lo ~ f32 fidelity).
__device__ inline void split8(const float* __restrict__ p, bf16x8& h, bf16x8& l) {
#pragma unroll
    for (int i = 0; i < 8; ++i) {
        float v = p[i];
        __bf16 hv = (__bf16)v;
        h[i] = hv;
        l[i] = (__bf16)(v - (float)hv);
    }
}
// Load 4 consecutive elements as f32 from f32-or-bf16 memory.
__device__ inline f32x4 load4(const void* __restrict__ p, size_t idx, bool f) {
    if (f) return *(const f32x4*)((const float*)p + idx);
    const __bf16* b = (const __bf16*)p + idx;
    f32x4 v;
    v[0] = (float)b[0]; v[1] = (float)b[1]; v[2] = (float)b[2]; v[3] = (float)b[3];
    return v;
}

// =====================================================================
// Input-dtype detection: flag=1 -> f32 inputs/outputs, flag=0 -> bf16.
// =====================================================================
__global__ __launch_bounds__(256) void detect_k(const void* __restrict__ x,
                                                int* __restrict__ flag) {
    const __bf16* p = (const __bf16*)x;
    int tid = threadIdx.x;
    bool bad = false;
    for (int i = 0; i < 16; ++i) {
        float v = fabsf((float)p[tid * 16 + i]);
        if (!(v <= 1e10f)) bad = true;    // catches huge AND NaN
    }
    unsigned long long m = __ballot(bad);
    __shared__ unsigned long long w[4];
    if ((tid & 63) == 0) w[tid >> 6] = m;
    __syncthreads();
    if (tid == 0) flag[0] = ((w[0] | w[1] | w[2] | w[3]) != 0ULL) ? 1 : 0;
}

// =====================================================================
// Convert x to bf16, 8 elements/thread.
// =====================================================================
__global__ __launch_bounds__(256) void convert_x_k(const void* __restrict__ x,
                                                   __bf16* __restrict__ xb,
                                                   const int* __restrict__ flag) {
    int i0 = (blockIdx.x * 256 + threadIdx.x) * 8;
    if (*flag) {
        const float* xf = (const float*)x;
        bf16x8 o;
        for (int i = 0; i < 8; ++i) o[i] = (__bf16)xf[i0 + i];
        *(bf16x8*)(xb + i0) = o;
    } else {
        *(bf16x8*)(xb + i0) = *(const bf16x8*)((const __bf16*)x + i0);
    }
}

// =====================================================================
// Tile transpose + convert: out[c][r] = (bf16)in[r][c]
// =====================================================================
__global__ __launch_bounds__(256) void transpose_cvt_k(const void* __restrict__ in,
                                                       __bf16* __restrict__ out, int R, int C,
                                                       const int* __restrict__ flag) {
    __shared__ __bf16 tile[32][33];
    bool f = (*flag != 0);
    int cb = blockIdx.x * 32, rb = blockIdx.y * 32;
    int tx = threadIdx.x & 31, ty = threadIdx.x >> 5;   // 32 x 8
    for (int i = 0; i < 32; i += 8) {
        size_t idx = (size_t)(rb + ty + i) * C + cb + tx;
        float v = f ? ((const float*)in)[idx] : (float)((const __bf16*)in)[idx];
        tile[ty + i][tx] = (__bf16)v;
    }
    __syncthreads();
    for (int i = 0; i < 32; i += 8)
        out[(size_t)(cb + ty + i) * R + rb + tx] = tile[tx][ty + i];
}

// =====================================================================
// bf16 NT GEMM: C[M][N] = A[M][K] @ Bt[N][K]^T, f32 acc.
// =====================================================================
__global__ __launch_bounds__(256) void gemm_nt_k(const __bf16* __restrict__ A,
                                                 const __bf16* __restrict__ Bt,
                                                 void* __restrict__ C, int M, int N, int K,
                                                 int f32out, const int* __restrict__ flag) {
    int bm = blockIdx.x, bn = blockIdx.y;
    __shared__ __bf16 As[128][72];
    __shared__ __bf16 Bs[128][72];
    int tid = threadIdx.x, wave = tid >> 6, lane = tid & 63;
    int quad = lane >> 4, l16 = lane & 15;
    int wm = (wave >> 1) * 64, wn = (wave & 1) * 64;
    const f32x4 z4 = {0.f, 0.f, 0.f, 0.f};
    f32x4 acc[4][4];
    for (int a = 0; a < 4; ++a) for (int b = 0; b < 4; ++b) acc[a][b] = z4;
    int srow = tid >> 1, sk0 = (tid & 1) * 32;
    const __bf16* Ap = A  + (size_t)(bm * 128 + srow) * K + sk0;
    const __bf16* Bp = Bt + (size_t)(bn * 128 + srow) * K + sk0;
    for (int k0 = 0; k0 < K; k0 += 64) {
        *(bf16x8*)&As[srow][sk0 +  0] = *(const bf16x8*)(Ap + k0 +  0);
        *(bf16x8*)&As[srow][sk0 +  8] = *(const bf16x8*)(Ap + k0 +  8);
        *(bf16x8*)&As[srow][sk0 + 16] = *(const bf16x8*)(Ap + k0 + 16);
        *(bf16x8*)&As[srow][sk0 + 24] = *(const bf16x8*)(Ap + k0 + 24);
        *(bf16x8*)&Bs[srow][sk0 +  0] = *(const bf16x8*)(Bp + k0 +  0);
        *(bf16x8*)&Bs[srow][sk0 +  8] = *(const bf16x8*)(Bp + k0 +  8);
        *(bf16x8*)&Bs[srow][sk0 + 16] = *(const bf16x8*)(Bp + k0 + 16);
        *(bf16x8*)&Bs[srow][sk0 + 24] = *(const bf16x8*)(Bp + k0 + 24);
        __syncthreads();
        for (int ks = 0; ks < 2; ++ks) {
            bf16x8 af[4], bfr[4];
            for (int mt = 0; mt < 4; ++mt)
                af[mt]  = *(const bf16x8*)&As[wm + mt * 16 + l16][ks * 32 + quad * 8];
            for (int nt = 0; nt < 4; ++nt)
                bfr[nt] = *(const bf16x8*)&Bs[wn + nt * 16 + l16][ks * 32 + quad * 8];
            for (int mt = 0; mt < 4; ++mt)
                for (int nt = 0; nt < 4; ++nt)
                    acc[mt][nt] = __builtin_amdgcn_mfma_f32_16x16x32_bf16(af[mt], bfr[nt], acc[mt][nt], 0, 0, 0);
        }
        __syncthreads();
    }
    bool f32o = f32out && (*flag != 0);
    for (int mt = 0; mt < 4; ++mt)
        for (int nt = 0; nt < 4; ++nt) {
            int rowb = bm * 128 + wm + mt * 16 + quad * 4;
            int col  = bn * 128 + wn + nt * 16 + l16;
            if (f32o) {
                for (int r = 0; r < 4; ++r)
                    ((float*)C)[(size_t)(rowb + r) * N + col] = acc[mt][nt][r];
            } else {
                for (int r = 0; r < 4; ++r)
                    ((__bf16*)C)[(size_t)(rowb + r) * N + col] = (__bf16)acc[mt][nt][r];
            }
        }
}

// =====================================================================
// Split-bf16 f32-fidelity GEMM: C_f32[M][N] = A[M][K] @ B[K][N].
// =====================================================================
__global__ __launch_bounds__(256) void gemm_split_f32_k(const void* __restrict__ A,
                                                        const void* __restrict__ B,
                                                        float* __restrict__ C,
                                                        int M, int N, int K,
                                                        const int* __restrict__ flag) {
    bool f = (*flag != 0);
    int bm = blockIdx.x, bn = blockIdx.y;
    __shared__ float Asf[128][36];
    __shared__ float Bsf[128][36];
    int tid = threadIdx.x, wave = tid >> 6, lane = tid & 63;
    int quad = lane >> 4, l16 = lane & 15;
    int wm = (wave >> 1) * 64, wn = (wave & 1) * 64;
    const f32x4 z4 = {0.f, 0.f, 0.f, 0.f};
    f32x4 acc[4][4];
    for (int a = 0; a < 4; ++a) for (int b = 0; b < 4; ++b) acc[a][b] = z4;
    int arow = tid >> 1, acol = (tid & 1) * 16;
    for (int k0 = 0; k0 < K; k0 += 32) {
        for (int g = 0; g < 4; ++g) {
            f32x4 v = load4(A, (size_t)(bm * 128 + arow) * K + k0 + acol + g * 4, f);
            *(f32x4*)&Asf[arow][acol + g * 4] = v;
        }
        for (int it = 0; it < 4; ++it) {
            int g = tid + it * 256;
            int krow = g >> 5, ng = (g & 31) * 4;
            f32x4 v = load4(B, (size_t)(k0 + krow) * N + bn * 128 + ng, f);
            Bsf[ng + 0][krow] = v[0];
            Bsf[ng + 1][krow] = v[1];
            Bsf[ng + 2][krow] = v[2];
            Bsf[ng + 3][krow] = v[3];
        }
        __syncthreads();
        bf16x8 ah[4], al[4], bh[4], bl[4];
        for (int mt = 0; mt < 4; ++mt) split8(&Asf[wm + mt * 16 + l16][quad * 8], ah[mt], al[mt]);
        for (int nt = 0; nt < 4; ++nt) split8(&Bsf[wn + nt * 16 + l16][quad * 8], bh[nt], bl[nt]);
        for (int mt = 0; mt < 4; ++mt)
            for (int nt = 0; nt < 4; ++nt) {
                acc[mt][nt] = __builtin_amdgcn_mfma_f32_16x16x32_bf16(al[mt], bh[nt], acc[mt][nt], 0, 0, 0);
                acc[mt][nt] = __builtin_amdgcn_mfma_f32_16x16x32_bf16(ah[mt], bl[nt], acc[mt][nt], 0, 0, 0);
                acc[mt][nt] = __builtin_amdgcn_mfma_f32_16x16x32_bf16(ah[mt], bh[nt], acc[mt][nt], 0, 0, 0);
            }
        __syncthreads();
    }
    for (int mt = 0; mt < 4; ++mt)
        for (int nt = 0; nt < 4; ++nt)
            for (int r = 0; r < 4; ++r)
                C[(size_t)(bm * 128 + wm + mt * 16 + quad * 4 + r) * N + bn * 128 + wn + nt * 16 + l16] = acc[mt][nt][r];
}

// =====================================================================
// RoPE in place on Qb (bf16, S x 2048).
// =====================================================================
__global__ __launch_bounds__(256) void rope_k(__bf16* __restrict__ Qb,
                                              const void* __restrict__ fc,
                                              const void* __restrict__ fs,
                                              const int* __restrict__ flag) {
    int idx = blockIdx.x * 256 + threadIdx.x;   // SEQ*NH*32 = 4194304 threads
    int t = idx >> 10;
    int r = idx & 1023;
    int j = r & 31;
    __bf16* p = Qb + (size_t)t * DIMM + (r >> 5) * HD + 2 * j;
    float c, s;
    if (*flag) {
        c = ((const float*)fc)[t * 32 + j];
        s = ((const float*)fs)[t * 32 + j];
    } else {
        c = (float)((const __bf16*)fc)[t * 32 + j];
        s = (float)((const __bf16*)fs)[t * 32 + j];
    }
    float xr = (float)p[0], xi = (float)p[1];
    p[0] = (__bf16)(xr * c - xi * s);
    p[1] = (__bf16)(xr * s + xi * c);
}

// =====================================================================
// RoPE in place (f32) on Kf32 (S x 512) and Qef32 (first 64 rows x 2048).
// =====================================================================
__global__ __launch_bounds__(256) void rope_f32_k(float* __restrict__ Kf,
                                                  float* __restrict__ Qe,
                                                  const void* __restrict__ fc,
                                                  const void* __restrict__ fs,
                                                  const int* __restrict__ flag) {
    int idx = blockIdx.x * 256 + threadIdx.x;
    const int NKP = SEQ * NKV * 32;   // 1048576
    const int NQP = 64 * NH * 32;     // 65536
    float* p; int t, j;
    if (idx < NKP) {
        t = idx >> 8; int r = idx & 255; j = r & 31;
        p = Kf + (size_t)t * (NKV * HD) + (r >> 5) * HD + 2 * j;
    } else {
        int k = idx - NKP;
        if (k >= NQP) return;
        t = k >> 10; int r = k & 1023; j = r & 31;
        p = Qe + (size_t)t * DIMM + (r >> 5) * HD + 2 * j;
    }
    float c, s;
    if (*flag) {
        c = ((const float*)fc)[t * 32 + j];
        s = ((const float*)fs)[t * 32 + j];
    } else {
        c = (float)((const __bf16*)fc)[t * 32 + j];
        s = (float)((const __bf16*)fs)[t * 32 + j];
    }
    float xr = p[0], xi = p[1];
    p[0] = xr * c - xi * s;
    p[1] = xr * s + xi * c;
}

// =====================================================================
// Kf32 (post-rope) -> Kb bf16 for the sparse-attention value path.
// =====================================================================
__global__ __launch_bounds__(256) void kf_to_bf16_k(const float* __restrict__ Kf,
                                                    __bf16* __restrict__ Kb) {
    int i0 = (blockIdx.x * 256 + threadIdx.x) * 8;
    bf16x8 o;
    for (int i = 0; i < 8; ++i) o[i] = (__bf16)Kf[i0 + i];
    *(bf16x8*)(Kb + i0) = o;
}

// =====================================================================
// Estimation partial row stats over a 512-key slice. grid (32 heads, 8).
// =====================================================================
__global__ __launch_bounds__(256) void est_part_k(const float* __restrict__ Qe,
                                                  const float* __restrict__ Kf,
                                                  float* __restrict__ pm,
                                                  float* __restrict__ ps) {
    int h = blockIdx.x, sl = blockIdx.y;
    int tid = threadIdx.x, wave = tid >> 6, lane = tid & 63;
    int quad = lane >> 4, l16 = lane & 15;
    __shared__ float Ml[64];
    __shared__ float pA[4][64];
    bf16x8 qh[4][2], ql[4][2];
    for (int mt = 0; mt < 4; ++mt)
        for (int kc = 0; kc < 2; ++kc)
            split8(Qe + (size_t)(mt * 16 + l16) * DIMM + h * HD + kc * 32 + quad * 8,
                   qh[mt][kc], ql[mt][kc]);
    int kvoff = (h >> 2) * HD;
    // ---- pass A: slice max ----
    float pmax[4][4];
    for (int mt = 0; mt < 4; ++mt) for (int r = 0; r < 4; ++r) pmax[mt][r] = -3.0e38f;
    for (int jb = wave; jb < 8; jb += 4)
        for (int c = 0; c < 4; ++c) {
            int j0 = sl * 512 + jb * 64 + c * 16;
            const float* kp = Kf + (size_t)(j0 + l16) * (NKV * HD) + kvoff + quad * 8;
            bf16x8 kh0, kl0, kh1, kl1;
            split8(kp, kh0, kl0);
            split8(kp + 32, kh1, kl1);
            int j = j0 + l16;
            for (int mt = 0; mt < 4; ++mt) {
                f32x4 acc = {0.f, 0.f, 0.f, 0.f};
                acc = __builtin_amdgcn_mfma_f32_16x16x32_bf16(ql[mt][0], kh0, acc, 0, 0, 0);
                acc = __builtin_amdgcn_mfma_f32_16x16x32_bf16(qh[mt][0], kl0, acc, 0, 0, 0);
                acc = __builtin_amdgcn_mfma_f32_16x16x32_bf16(qh[mt][0], kh0, acc, 0, 0, 0);
                acc = __builtin_amdgcn_mfma_f32_16x16x32_bf16(ql[mt][1], kh1, acc, 0, 0, 0);
                acc = __builtin_amdgcn_mfma_f32_16x16x32_bf16(qh[mt][1], kl1, acc, 0, 0, 0);
                acc = __builtin_amdgcn_mfma_f32_16x16x32_bf16(qh[mt][1], kh1, acc, 0, 0, 0);
                for (int r = 0; r < 4; ++r) {
                    int q = mt * 16 + quad * 4 + r;
                    float sv = acc[r] * 0.125f;
                    if (j >= SEQ - 64 && q < j - (SEQ - 64)) sv = -1e30f;
                    pmax[mt][r] = fmaxf(pmax[mt][r], sv);
                }
            }
        }
    for (int mt = 0; mt < 4; ++mt)
        for (int r = 0; r < 4; ++r)
            for (int m2 = 1; m2 < 16; m2 <<= 1)
                pmax[mt][r] = fmaxf(pmax[mt][r], __shfl_xor(pmax[mt][r], m2));
    if (l16 == 0)
        for (int mt = 0; mt < 4; ++mt)
            for (int r = 0; r < 4; ++r)
                pA[wave][mt * 16 + quad * 4 + r] = pmax[mt][r];
    __syncthreads();
    if (tid < 64)
        Ml[tid] = fmaxf(fmaxf(pA[0][tid], pA[1][tid]), fmaxf(pA[2][tid], pA[3][tid]));
    __syncthreads();
    float mreg[4][4];
    for (int mt = 0; mt < 4; ++mt)
        for (int r = 0; r < 4; ++r)
            mreg[mt][r] = Ml[mt * 16 + quad * 4 + r];
    // ---- pass B: slice sum ----
    float psum[4][4];
    for (int mt = 0; mt < 4; ++mt) for (int r = 0; r < 4; ++r) psum[mt][r] = 0.f;
    for (int jb = wave; jb < 8; jb += 4)
        for (int c = 0; c < 4; ++c) {
            int j0 = sl * 512 + jb * 64 + c * 16;
            const float* kp = Kf + (size_t)(j0 + l16) * (NKV * HD) + kvoff + quad * 8;
            bf16x8 kh0, kl0, kh1, kl1;
            split8(kp, kh0, kl0);
            split8(kp + 32, kh1, kl1);
            int j = j0 + l16;
            for (int mt = 0; mt < 4; ++mt) {
                f32x4 acc = {0.f, 0.f, 0.f, 0.f};
                acc = __builtin_amdgcn_mfma_f32_16x16x32_bf16(ql[mt][0], kh0, acc, 0, 0, 0);
                acc = __builtin_amdgcn_mfma_f32_16x16x32_bf16(qh[mt][0], kl0, acc, 0, 0, 0);
                acc = __builtin_amdgcn_mfma_f32_16x16x32_bf16(qh[mt][0], kh0, acc, 0, 0, 0);
                acc = __builtin_amdgcn_mfma_f32_16x16x32_bf16(ql[mt][1], kh1, acc, 0, 0, 0);
                acc = __builtin_amdgcn_mfma_f32_16x16x32_bf16(qh[mt][1], kl1, acc, 0, 0, 0);
                acc = __builtin_amdgcn_mfma_f32_16x16x32_bf16(qh[mt][1], kh1, acc, 0, 0, 0);
                for (int r = 0; r < 4; ++r) {
                    int q = mt * 16 + quad * 4 + r;
                    float sv = acc[r] * 0.125f;
                    if (j >= SEQ - 64 && q < j - (SEQ - 64)) sv = -1e30f;
                    psum[mt][r] += __expf(sv - mreg[mt][r]);
                }
            }
        }
    for (int mt = 0; mt < 4; ++mt)
        for (int r = 0; r < 4; ++r)
            for (int m2 = 1; m2 < 16; m2 <<= 1)
                psum[mt][r] += __shfl_xor(psum[mt][r], m2);
    if (l16 == 0)
        for (int mt = 0; mt < 4; ++mt)
            for (int r = 0; r < 4; ++r)
                pA[wave][mt * 16 + quad * 4 + r] = psum[mt][r];
    __syncthreads();
    if (tid < 64) {
        pm[(h * 8 + sl) * 64 + tid] = Ml[tid];
        ps[(h * 8 + sl) * 64 + tid] = pA[0][tid] + pA[1][tid] + pA[2][tid] + pA[3][tid];
    }
}

// Combine 8 slice partials -> rmax/rsum. grid 32, block 64.
__global__ __launch_bounds__(64) void est_comb_k(const float* __restrict__ pm,
                                                 const float* __restrict__ ps,
                                                 float* __restrict__ rmax,
                                                 float* __restrict__ rsum) {
    int h = blockIdx.x, q = threadIdx.x;
    float M = -3.0e38f;
    for (int sl = 0; sl < 8; ++sl) M = fmaxf(M, pm[(h * 8 + sl) * 64 + q]);
    float S = 0.f;
    for (int sl = 0; sl < 8; ++sl)
        S += ps[(h * 8 + sl) * 64 + q] * __expf(pm[(h * 8 + sl) * 64 + q] - M);
    rmax[h * 64 + q] = M;
    rsum[h * 64 + q] = S;
}

__global__ __launch_bounds__(256) void zerof_k(float* __restrict__ p, int n) {
    int i = blockIdx.x * 256 + threadIdx.x;
    if (i < n) p[i] = 0.f;
}

// =====================================================================
// vertical[h][j] = sum_q probs; diag[h][g] += sum_q probs[q][g+q-63]
// grid (32 heads, 32 key-chunks of 128). f32-fidelity logits via split.
// =====================================================================
__global__ __launch_bounds__(256) void vert_diag_k(const float* __restrict__ Qe,
                                                   const float* __restrict__ Kf,
                                                   const float* __restrict__ rmax,
                                                   const float* __restrict__ rsum,
                                                   float* __restrict__ vert,
                                                   float* __restrict__ diag) {
    int h = blockIdx.x, jb = blockIdx.y;
    int tid = threadIdx.x, wave = tid >> 6, lane = tid & 63;
    int quad = lane >> 4, l16 = lane & 15;
    __shared__ float P[64][132];
    __shared__ float dloc[192];
    for (int i = tid; i < 192; i += 256) dloc[i] = 0.f;
    bf16x8 qh[4][2], ql[4][2];
    for (int mt = 0; mt < 4; ++mt)
        for (int kc = 0; kc < 2; ++kc)
            split8(Qe + (size_t)(mt * 16 + l16) * DIMM + h * HD + kc * 32 + quad * 8,
                   qh[mt][kc], ql[mt][kc]);
    float rm[4][4], rs[4][4];
    for (int mt = 0; mt < 4; ++mt)
        for (int r = 0; r < 4; ++r) {
            int q = mt * 16 + quad * 4 + r;
            rm[mt][r] = rmax[h * 64 + q];
            rs[mt][r] = rsum[h * 64 + q];
        }
    int kvoff = (h >> 2) * HD;
    for (int c = 0; c < 2; ++c) {
        int jl0 = wave * 32 + c * 16;
        int j0 = jb * 128 + jl0;
        const float* kp = Kf + (size_t)(j0 + l16) * (NKV * HD) + kvoff + quad * 8;
        bf16x8 kh0, kl0, kh1, kl1;
        split8(kp, kh0, kl0);
        split8(kp + 32, kh1, kl1);
        int j = j0 + l16;
        for (int mt = 0; mt < 4; ++mt) {
            f32x4 acc = {0.f, 0.f, 0.f, 0.f};
            acc = __builtin_amdgcn_mfma_f32_16x16x32_bf16(ql[mt][0], kh0, acc, 0, 0, 0);
            acc = __builtin_amdgcn_mfma_f32_16x16x32_bf16(qh[mt][0], kl0, acc, 0, 0, 0);
            acc = __builtin_amdgcn_mfma_f32_16x16x32_bf16(qh[mt][0], kh0, acc, 0, 0, 0);
            acc = __builtin_amdgcn_mfma_f32_16x16x32_bf16(ql[mt][1], kh1, acc, 0, 0, 0);
            acc = __builtin_amdgcn_mfma_f32_16x16x32_bf16(qh[mt][1], kl1, acc, 0, 0, 0);
            acc = __builtin_amdgcn_mfma_f32_16x16x32_bf16(qh[mt][1], kh1, acc, 0, 0, 0);
            for (int r = 0; r < 4; ++r) {
                int q = mt * 16 + quad * 4 + r;
                float sv = acc[r] * 0.125f;
                if (j >= SEQ - 64 && q < j - (SEQ - 64)) sv = -1e30f;
                P[q][jl0 + l16] = __expf(sv - rm[mt][r]) / rs[mt][r];
            }
        }
    }
    __syncthreads();
    if (tid < 128) {
        float vacc = 0.f;
        for (int q = 0; q < 64; ++q) {
            float pb = P[q][tid];
            vacc += pb;
            if (jb * 128 + tid + 63 - q < SEQ) atomicAdd(&dloc[tid + 63 - q], pb);
        }
        vert[h * SEQ + jb * 128 + tid] = vacc;
    }
    __syncthreads();
    for (int i = tid; i < 192; i += 256) {
        int g = jb * 128 + i;
        if (g < SEQ) atomicAdd(&diag[h * SEQ + g], dloc[i]);
    }
}

// =====================================================================
// Per-head top-k WITHOUT sorting:
//  - 4-pass MSB radix-select on f32 bits (all values > 0 so bit order =
//    value order); jax tie-break (lowest index first) via index-ordered
//    rank among threshold-equal elements.
//  - merge vert top-300 (key=idx) + diag top-800 (key=4095-idx), then
//    counting-sort (occupancy 0..2 per key) -> skeys ascending.
// One block per head; per-wave histogram copies cut LDS atomic serialization.
// =====================================================================
__global__ __launch_bounds__(256) void topk_merge_k(const float* __restrict__ vert,
                                                    const float* __restrict__ diag,
                                                    int* __restrict__ skeys) {
    __shared__ int cnt[4096];
    __shared__ int hist4[4][256];
    __shared__ int scanb[256];
    __shared__ int B_sh, kk_sh;
    int h = blockIdx.x, tid = threadIdx.x, wave = tid >> 6;
    for (int i = tid; i < 4096; i += 256) cnt[i] = 0;
    __syncthreads();
    for (int selp = 0; selp < 2; ++selp) {
        const float* vals = (selp == 0 ? vert : diag) + h * SEQ;
        int k = (selp == 0) ? 300 : 800;
        bool flip = (selp == 1);
        unsigned bits[16];
        for (int g = 0; g < 4; ++g) {
            f32x4 v = *(const f32x4*)(vals + tid * 16 + g * 4);
            for (int e = 0; e < 4; ++e) bits[g * 4 + e] = __float_as_uint(v[e]);
        }
        unsigned prefix = 0;
        int kk = k;
        for (int pass = 0; pass < 4; ++pass) {
            int sh = 8 * (3 - pass);
            for (int w = 0; w < 4; ++w) hist4[w][tid & 255] = 0;
            __syncthreads();
            for (int e = 0; e < 16; ++e) {
                unsigned b = bits[e];
                bool in = (pass == 0) || ((b >> (sh + 8)) == prefix);
                if (in) atomicAdd(&hist4[wave][(b >> sh) & 255], 1);
            }
            __syncthreads();
            if (tid == 0) {
                int running = 0, B = 0;
                for (int bin = 255; bin >= 0; --bin) {
                    int hb = hist4[0][bin] + hist4[1][bin] + hist4[2][bin] + hist4[3][bin];
                    if (kk <= running + hb) { B = bin; break; }
                    running += hb;
                }
                B_sh = B; kk_sh = kk - running;
            }
            __syncthreads();
            prefix = (prefix << 8) | (unsigned)B_sh;
            kk = kk_sh;
            __syncthreads();
        }
        // mark strictly-greater; count equals (index-ordered: contiguous chunks)
        int localEq = 0;
        for (int e = 0; e < 16; ++e) {
            unsigned b = bits[e];
            if (b > prefix) {
                int idx = tid * 16 + e;
                atomicAdd(&cnt[flip ? (4095 - idx) : idx], 1);
            } else if (b == prefix) ++localEq;
        }
        scanb[tid] = localEq;
        __syncthreads();
        for (int off = 1; off < 256; off <<= 1) {
            int v = (tid >= off) ? scanb[tid - off] : 0;
            __syncthreads();
            scanb[tid] += v;
            __syncthreads();
        }
        int eqOff = scanb[tid] - localEq;   // exclusive, in global index order
        int taken = 0;
        for (int e = 0; e < 16; ++e) {
            unsigned b = bits[e];
            if (b == prefix) {
                if (eqOff + taken < kk) {
                    int idx = tid * 16 + e;
                    atomicAdd(&cnt[flip ? (4095 - idx) : idx], 1);
                }
                ++taken;
            }
        }
        __syncthreads();
    }
    // counting sort: cnt[idx] in {0,1,2}, total = 1100
    int base = tid * 16;
    int loc[16];
    int s = 0;
    for (int e = 0; e < 16; ++e) { loc[e] = s; s += cnt[base + e]; }
    scanb[tid] = s;
    __syncthreads();
    for (int off = 1; off < 256; off <<= 1) {
        int v = (tid >= off) ? scanb[tid - off] : 0;
        __syncthreads();
        scanb[tid] += v;
        __syncthreads();
    }
    int chunkExcl = scanb[tid] - s;
    int* out = skeys + h * NSPP;
    for (int e = 0; e < 16; ++e) {
        int c = cnt[base + e];
        int pos = chunkExcl + loc[e];
        for (int r = 0; r < c; ++r) out[pos + r] = base + e;
    }
    for (int i = NSP + tid; i < NSPP; i += 256) out[i] = 0x7fffffff;
}

// =====================================================================
// Gather sparse K (keys x 64) and V transposed (64 x keys). Pads zeroed.
// =====================================================================
__global__ __launch_bounds__(256) void gather_k(const __bf16* __restrict__ Kb,
                                                const __bf16* __restrict__ Vb,
                                                const int* __restrict__ skeys,
                                                __bf16* __restrict__ Ksp,
                                                __bf16* __restrict__ VspT) {
    int idx = blockIdx.x * 256 + threadIdx.x;
    if (idx >= NH * NSPP) return;
    int h = idx / NSPP, j = idx % NSPP;
    int t = skeys[idx];
    int kv = (h >> 2) * HD;
    __bf16* kd = Ksp + (size_t)idx * HD;
    __bf16* vt = VspT + (size_t)h * HD * NSPP + j;
    if ((unsigned)t < SEQ) {
        const __bf16* ks = Kb + (size_t)t * (NKV * HD) + kv;
        const __bf16* vs = Vb + (size_t)t * (NKV * HD) + kv;
        for (int d8 = 0; d8 < 8; ++d8)
            *(bf16x8*)(kd + d8 * 8) = *(const bf16x8*)(ks + d8 * 8);
        for (int d = 0; d < HD; ++d) vt[(size_t)d * NSPP] = vs[d];
    } else {
        const bf16x8 z = {};
        for (int d8 = 0; d8 < 8; ++d8) *(bf16x8*)(kd + d8 * 8) = z;
        for (int d = 0; d < HD; ++d) vt[(size_t)d * NSPP] = (__bf16)0.f;
    }
}

// =====================================================================
// Sparse attention: grid (128 q-tiles of 32, 32 heads). 4 waves/block.
// =====================================================================
__global__ __launch_bounds__(256) void sparse_attn_k(const __bf16* __restrict__ Qb,
                                                     const __bf16* __restrict__ Ksp,
                                                     const __bf16* __restrict__ VspT,
                                                     const int* __restrict__ skeys,
                                                     __bf16* __restrict__ AO) {
    int qb = blockIdx.x, h = blockIdx.y;
    int tid = threadIdx.x, wave = tid >> 6, lane = tid & 63;
    int quad = lane >> 4, l16 = lane & 15;
    __shared__ __bf16 sc[32][1160];     // logits then P; stride 1160 (bank-spread)
    __shared__ float rsm[32];
    int t0 = qb * 32;
    bf16x8 aq[2][2];
    for (int qs = 0; qs < 2; ++qs)
        for (int kc = 0; kc < 2; ++kc)
            aq[qs][kc] = *(const bf16x8*)(Qb + (size_t)(t0 + qs * 16 + l16) * DIMM + h * HD + kc * 32 + quad * 8);
    const __bf16* Kh = Ksp + (size_t)h * NSPP * HD;
    const int* sk = skeys + h * NSPP;
    // ---- phase 1: QK^T ----
    for (int c = 0; c < 18; ++c) {
        int j0 = wave * 288 + c * 16;
        const __bf16* kp = Kh + (size_t)(j0 + l16) * HD + quad * 8;
        bf16x8 b0 = *(const bf16x8*)kp;
        bf16x8 b1 = *(const bf16x8*)(kp + 32);
        int j = j0 + l16;
        int key = sk[j];                 // pads hold INT_MAX -> always masked
        for (int qs = 0; qs < 2; ++qs) {
            f32x4 acc = {0.f, 0.f, 0.f, 0.f};
            acc = __builtin_amdgcn_mfma_f32_16x16x32_bf16(aq[qs][0], b0, acc, 0, 0, 0);
            acc = __builtin_amdgcn_mfma_f32_16x16x32_bf16(aq[qs][1], b1, acc, 0, 0, 0);
            int qg = t0 + qs * 16 + quad * 4;
            for (int r = 0; r < 4; ++r) {
                float sv = acc[r] * 0.125f;
                if (key > qg + r) sv = -1e30f;     // causal (finite, matches ref)
                sc[qs * 16 + quad * 4 + r][j] = (__bf16)sv;
            }
        }
    }
    __syncthreads();
    // ---- phase 2: softmax; 8 lanes/row, 144 consecutive cols each ----
    {
        int row = tid >> 3, sub = tid & 7;
        int c0 = sub * 144;
        float mx = -3.0e38f;
        for (int i = 0; i < 18; ++i) {
            bf16x8 v = *(const bf16x8*)&sc[row][c0 + i * 8];
            for (int e = 0; e < 8; ++e) mx = fmaxf(mx, (float)v[e]);
        }
        for (int m2 = 1; m2 < 8; m2 <<= 1) mx = fmaxf(mx, __shfl_xor(mx, m2, 8));
        float sm = 0.f;
        for (int i = 0; i < 18; ++i) {
            int cb = c0 + i * 8;
            bf16x8 v = *(const bf16x8*)&sc[row][cb];
            bf16x8 pw;
            for (int e = 0; e < 8; ++e) {
                float pv = 0.f;
                if (cb + e < NSP) { pv = __expf((float)v[e] - mx); sm += pv; }
                pw[e] = (__bf16)pv;
            }
            *(bf16x8*)&sc[row][cb] = pw;
        }
        for (int m2 = 1; m2 < 8; m2 <<= 1) sm += __shfl_xor(sm, m2, 8);
        if (sub == 0) rsm[row] = sm;
    }
    __syncthreads();
    // ---- phase 3: PV; wave -> (q-subtile, d-half) ----
    int qs = wave >> 1, dh = wave & 1;
    const f32x4 z4 = {0.f, 0.f, 0.f, 0.f};
    f32x4 o0 = z4, o1 = z4;
    const __bf16* Vh = VspT + ((size_t)h * HD + dh * 32) * NSPP;
    for (int c = 0; c < 36; ++c) {
        int kb = c * 32;
        bf16x8 pa = *(const bf16x8*)&sc[qs * 16 + l16][kb + quad * 8];
        bf16x8 v0 = *(const bf16x8*)(Vh + (size_t)l16 * NSPP + kb + quad * 8);
        bf16x8 v1 = *(const bf16x8*)(Vh + (size_t)(16 + l16) * NSPP + kb + quad * 8);
        o0 = __builtin_amdgcn_mfma_f32_16x16x32_bf16(pa, v0, o0, 0, 0, 0);
        o1 = __builtin_amdgcn_mfma_f32_16x16x32_bf16(pa, v1, o1, 0, 0, 0);
    }
    for (int r = 0; r < 4; ++r) {
        int ql = qs * 16 + quad * 4 + r;
        float inv = 1.f / rsm[ql];
        size_t base = (size_t)(t0 + ql) * DIMM + h * HD + dh * 32;
        AO[base + l16]      = (__bf16)(o0[r] * inv);
        AO[base + 16 + l16] = (__bf16)(o1[r] * inv);
    }
}

// =====================================================================
// Launch. Workspace (~52.7 MiB) — layout unchanged from round 5.
// =====================================================================
extern "C" void kernel_launch(void* const* d_in, const int* in_sizes, int n_in,
                              void* d_out, int out_size, void* d_ws, size_t ws_size,
                              hipStream_t stream) {
    const void* x  = d_in[0];
    const void* fc = d_in[1];
    const void* fs = d_in[2];
    const void* wq = d_in[3];
    const void* wk = d_in[4];
    const void* wv = d_in[5];
    const void* wo = d_in[6];
    char* ws = (char*)d_ws;

    __bf16* Qb   = (__bf16*)(ws + 0);
    __bf16* Kb   = (__bf16*)(ws + 16777216);
    __bf16* Vb   = (__bf16*)(ws + 20971520);
    __bf16* xbf  = (__bf16*)(ws + 25165824);   // UNION1
    float*  Kf32 = (float*)(ws + 25165824);    // after xbf dead
    float*  Qef32= (float*)(ws + 33554432);
    __bf16* AO   = (__bf16*)(ws + 25165824);   // after Kf32/Qef32 dead
    __bf16* Wt   = (__bf16*)(ws + 41943040);   // UNION2
    __bf16* Ksp  = (__bf16*)(ws + 41943040);
    __bf16* VspT = (__bf16*)(ws + 46661632);
    float*  rmax = (float*)(ws + 51380224);
    float*  rsum = (float*)(ws + 51388416);
    float*  vert = (float*)(ws + 51396608);
    float*  diag = (float*)(ws + 51920896);
    int*    skeys= (int*)(ws + 52445184);
    int*    flag = (int*)(ws + 52592640);
    float*  pm   = (float*)(ws + 52592896);
    float*  ps   = (float*)(ws + 52658432);

    dim3 b256(256);
    detect_k<<<1, b256, 0, stream>>>(x, flag);
    convert_x_k<<<4096, b256, 0, stream>>>(x, xbf, flag);
    // value-path projections (bf16)
    transpose_cvt_k<<<dim3(64, 64), b256, 0, stream>>>(wq, Wt, 2048, 2048, flag);
    gemm_nt_k<<<dim3(32, 16), b256, 0, stream>>>(xbf, Wt, Qb, 4096, 2048, 2048, 0, flag);
    transpose_cvt_k<<<dim3(16, 64), b256, 0, stream>>>(wv, Wt, 2048, 512, flag);
    gemm_nt_k<<<dim3(32, 4), b256, 0, stream>>>(xbf, Wt, Vb, 4096, 512, 2048, 0, flag);
    // selection-path projections (split-bf16 ~f32 fidelity); xbf dead now
    gemm_split_f32_k<<<dim3(32, 4), b256, 0, stream>>>(x, wk, Kf32, 4096, 512, 2048, flag);
    gemm_split_f32_k<<<dim3(1, 16), b256, 0, stream>>>(x, wq, Qef32, 128, 2048, 2048, flag);
    // rope
    rope_k<<<16384, b256, 0, stream>>>(Qb, fc, fs, flag);
    rope_f32_k<<<4352, b256, 0, stream>>>(Kf32, Qef32, fc, fs, flag);
    kf_to_bf16_k<<<1024, b256, 0, stream>>>(Kf32, Kb);
    // estimation (f32 fidelity), partial + combine
    est_part_k<<<dim3(32, 8), b256, 0, stream>>>(Qef32, Kf32, pm, ps);
    est_comb_k<<<32, dim3(64), 0, stream>>>(pm, ps, rmax, rsum);
    zerof_k<<<512, b256, 0, stream>>>(diag, 32 * SEQ);
    vert_diag_k<<<dim3(32, 32), b256, 0, stream>>>(Qef32, Kf32, rmax, rsum, vert, diag);
    topk_merge_k<<<32, b256, 0, stream>>>(vert, diag, skeys);
    // sparse attention (bf16); Kf32/Qef32 dead -> AO may reuse UNION1
    gather_k<<<144, b256, 0, stream>>>(Kb, Vb, skeys, Ksp, VspT);
    sparse_attn_k<<<dim3(128, 32), b256, 0, stream>>>(Qb, Ksp, VspT, skeys, AO);
    // output projection (f32 store if inputs were f32)
    transpose_cvt_k<<<dim3(64, 64), b256, 0, stream>>>(wo, Wt, 2048, 2048, flag);
    gemm_nt_k<<<dim3(32, 16), b256, 0, stream>>>(AO, Wt, d_out, 4096, 2048, 2048, 1, flag);
}